// Round 10
// baseline (725.309 us; speedup 1.0000x reference)
//
#include <hip/hip_runtime.h>
#include <cstdint>
#include <cstddef>

#define HID 128
#define N_USERS 100000
#define N_JOBS  50000
#define N_EDGES 2000000
#define N_LABELS 500000

#define RBITS 8
#define RSIZE 256
#define NBJ ((N_JOBS  + RSIZE - 1) / RSIZE)   // 196
#define NBU ((N_USERS + RSIZE - 1) / RSIZE)   // 391
#define P1CHUNK 8192

// GEMM tiling (64-row tiles)
#define TBU ((N_USERS + 63) / 64)   // 1563
#define TBJ ((N_JOBS  + 63) / 64)   // 782

typedef __attribute__((ext_vector_type(8))) short short8;
typedef __attribute__((ext_vector_type(4))) float f32x4;

__device__ __forceinline__ unsigned short f2b(float f) {
    union { float f; unsigned u; } v; v.f = f;
    unsigned r = v.u + 0x7FFFu + ((v.u >> 16) & 1u);   // RNE to bf16
    return (unsigned short)(r >> 16);
}
__device__ __forceinline__ float b2f(unsigned h) {
    union { unsigned u; float f; } v; v.u = h << 16;
    return v.f;
}
__device__ __forceinline__ unsigned pk2(float lo, float hi) {
    return (unsigned)f2b(lo) | ((unsigned)f2b(hi) << 16);
}
// async global->LDS, 16B per lane; LDS dest = wave-uniform base + lane*16
__device__ __forceinline__ void gl_lds16(const void* g, void* l) {
    __builtin_amdgcn_global_load_lds(
        (const __attribute__((address_space(1))) unsigned int*)g,
        (__attribute__((address_space(3))) unsigned int*)l, 16, 0, 0);
}

// ---------------------------------------------------------------------------
// One-shot: convert all 10 weight matrices fp32 -> bf16 into ws.
// Block 0 also zeroes the bucket-count arrays (replaces 2 memsets).
// ---------------------------------------------------------------------------
__global__ __launch_bounds__(256) void cvt_weights(
    const float* __restrict__ uW, const float* __restrict__ jW,
    const float* __restrict__ a, const float* __restrict__ b,
    const float* __restrict__ c, const float* __restrict__ d,
    const float* __restrict__ e, const float* __restrict__ f,
    const float* __restrict__ g, const float* __restrict__ h,
    unsigned short* __restrict__ ow,
    int* __restrict__ bcnt_j, int* __restrict__ bcnt_u) {
    if (blockIdx.x == 288) {   // dedicated zeroing block
        for (int i = threadIdx.x; i <= NBJ; i += 256) bcnt_j[i] = 0;
        for (int i = threadIdx.x; i <= NBU; i += 256) bcnt_u[i] = 0;
        return;
    }
    int i4 = blockIdx.x * 256 + threadIdx.x;   // float4 index
    if (i4 >= 73728) return;                    // 294912 floats total
    int i = i4 * 4;
    const float* src; int base;
    if (i < 65536)       { src = uW; base = 0; }
    else if (i < 163840) { src = jW; base = 65536; }
    else {
        int k = (i - 163840) >> 14;
        const float* s4 = (k < 4) ? ((k < 2) ? (k == 0 ? a : b) : (k == 2 ? c : d))
                                  : ((k < 6) ? (k == 4 ? e : f) : (k == 6 ? g : h));
        src = s4; base = 163840 + (k << 14);
    }
    float4 v = *reinterpret_cast<const float4*>(src + (i - base));
    *reinterpret_cast<uint2*>(ow + i) = make_uint2(pk2(v.x, v.y), pk2(v.z, v.w));
}

// ---------------------------------------------------------------------------
// CSR build stage 1: bucket histogram (both sides), LDS-aggregated
// ---------------------------------------------------------------------------
__global__ __launch_bounds__(256) void bucket_hist(const int* __restrict__ src,
                                                   const int* __restrict__ dst,
                                                   int nE, int* __restrict__ bcnt_j,
                                                   int* __restrict__ bcnt_u) {
    __shared__ int hj[NBJ];
    __shared__ int hu[NBU];
    int t = threadIdx.x;
    for (int i = t; i < NBJ; i += 256) hj[i] = 0;
    for (int i = t; i < NBU; i += 256) hu[i] = 0;
    __syncthreads();
    int i = blockIdx.x * blockDim.x + t;
    int stride = gridDim.x * blockDim.x;
    for (; i < nE; i += stride) {
        atomicAdd(&hj[dst[i] >> RBITS], 1);
        atomicAdd(&hu[src[i] >> RBITS], 1);
    }
    __syncthreads();
    for (int i2 = t; i2 < NBJ; i2 += 256) if (hj[i2]) atomicAdd(&bcnt_j[i2], hj[i2]);
    for (int i2 = t; i2 < NBU; i2 += 256) if (hu[i2]) atomicAdd(&bcnt_u[i2], hu[i2]);
}

// ---------------------------------------------------------------------------
// CSR build stage 2: exclusive scan of bucket counts (one block per side)
// ---------------------------------------------------------------------------
__global__ __launch_bounds__(1024) void bucket_scan(int* __restrict__ bcnt_j, int* __restrict__ boff_j,
                                                    int* __restrict__ bcur_j,
                                                    int* __restrict__ bcnt_u, int* __restrict__ boff_u,
                                                    int* __restrict__ bcur_u) {
    int* bcnt = blockIdx.x ? bcnt_u : bcnt_j;
    int* boff = blockIdx.x ? boff_u : boff_j;
    int* bcur = blockIdx.x ? bcur_u : bcur_j;
    int n = blockIdx.x ? NBU : NBJ;
    __shared__ int sm[1024];
    int t = threadIdx.x;
    int v = (t < n) ? bcnt[t] : 0;
    sm[t] = v;
    __syncthreads();
    for (int d = 1; d < 1024; d <<= 1) {
        int q = (t >= d) ? sm[t - d] : 0;
        __syncthreads();
        sm[t] += q;
        __syncthreads();
    }
    if (t < n) { int e = sm[t] - v; boff[t] = e; bcur[t] = e; }
    if (t == 0) boff[n] = N_EDGES;
}

// ---------------------------------------------------------------------------
// CSR build stage 3: LDS-binned radix partition (bulk-reserved runs)
// ---------------------------------------------------------------------------
__global__ __launch_bounds__(256) void csr_pass1(const int* __restrict__ src,
                                                 const int* __restrict__ dst,
                                                 int nE, int* __restrict__ gcur_j,
                                                 int* __restrict__ gcur_u,
                                                 unsigned* __restrict__ stage_j,
                                                 unsigned* __restrict__ stage_u) {
    __shared__ int cur_j[NBJ];
    __shared__ int cur_u[NBU];
    int t = threadIdx.x;
    int e0 = blockIdx.x * P1CHUNK;
    int e1 = min(e0 + P1CHUNK, nE);
    for (int i = t; i < NBJ; i += 256) cur_j[i] = 0;
    for (int i = t; i < NBU; i += 256) cur_u[i] = 0;
    __syncthreads();
    for (int e = e0 + t; e < e1; e += 256) {
        atomicAdd(&cur_j[dst[e] >> RBITS], 1);
        atomicAdd(&cur_u[src[e] >> RBITS], 1);
    }
    __syncthreads();
    for (int i = t; i < NBJ; i += 256) {
        int c = cur_j[i];
        cur_j[i] = c ? atomicAdd(&gcur_j[i], c) : 0;
    }
    for (int i = t; i < NBU; i += 256) {
        int c = cur_u[i];
        cur_u[i] = c ? atomicAdd(&gcur_u[i], c) : 0;
    }
    __syncthreads();
    for (int e = e0 + t; e < e1; e += 256) {
        int d = dst[e], s = src[e];
        int pj = atomicAdd(&cur_j[d >> RBITS], 1);
        stage_j[pj] = ((unsigned)(d & (RSIZE - 1)) << 24) | (unsigned)s;
        int pu = atomicAdd(&cur_u[s >> RBITS], 1);
        stage_u[pu] = ((unsigned)(s & (RSIZE - 1)) << 24) | (unsigned)d;
    }
}

// ---------------------------------------------------------------------------
// CSR build stage 4: per-bucket reorder (256 nodes/bucket)
// ---------------------------------------------------------------------------
__global__ __launch_bounds__(256) void csr_pass2(
    const unsigned* __restrict__ stage_j, const int* __restrict__ boff_j,
    int* __restrict__ off_j, int* __restrict__ vals_j,
    const unsigned* __restrict__ stage_u, const int* __restrict__ boff_u,
    int* __restrict__ off_u, int* __restrict__ vals_u) {
    __shared__ int cnt[RSIZE];
    __shared__ int sc[RSIZE];
    __shared__ int cur[RSIZE];
    int borig = blockIdx.x, t = threadIdx.x;
    const unsigned* words; const int* boff; int* off; int* vals; int b; int nNodes;
    if (borig < NBJ) { words = stage_j; boff = boff_j; off = off_j; vals = vals_j; b = borig; nNodes = N_JOBS; }
    else             { words = stage_u; boff = boff_u; off = off_u; vals = vals_u; b = borig - NBJ; nNodes = N_USERS; }
    int node0 = b << RBITS;
    int sbeg = boff[b], send = boff[b + 1];
    cnt[t] = 0;
    __syncthreads();
    for (int e = sbeg + t; e < send; e += 256) {
        atomicAdd(&cnt[words[e] >> 24], 1);
    }
    __syncthreads();
    int v = cnt[t];
    sc[t] = v;
    __syncthreads();
    #pragma unroll
    for (int d = 1; d < RSIZE; d <<= 1) {
        int q = (t >= d) ? sc[t - d] : 0;
        __syncthreads();
        sc[t] += q;
        __syncthreads();
    }
    int node = node0 + t;
    if (node < nNodes) {
        int base = sbeg + sc[t] - v;   // exclusive
        off[node] = base;
        cur[t] = base;
    }
    __syncthreads();
    for (int e = sbeg + t; e < send; e += 256) {
        unsigned w = words[e];
        int slot = atomicAdd(&cur[w >> 24], 1);
        vals[slot] = (int)(w & 0xFFFFFFu);
    }
    if (t == 0 && borig == 0)   off_j[N_JOBS]  = N_EDGES;
    if (t == 0 && borig == NBJ) off_u[N_USERS] = N_EDGES;
}

// ---------------------------------------------------------------------------
// FUSED encoder (user + job sides): out_bf16 = relu(BN(X @ W^T + b)).
// 64x128 tile, BK=64, async global_load_lds double-buffered X staging with
// 16B-unit XOR swizzle; W fragments prefetched into VGPRs.
// ---------------------------------------------------------------------------
__global__ __launch_bounds__(256) void encoder_mfma(
    const float* __restrict__ Xu, const unsigned short* __restrict__ Wbu,
    const float* __restrict__ bu, const float* __restrict__ gu,
    const float* __restrict__ beu, const float* __restrict__ mu,
    const float* __restrict__ vu,
    const float* __restrict__ Xj, const unsigned short* __restrict__ Wbj,
    const float* __restrict__ bj, const float* __restrict__ gj,
    const float* __restrict__ bej, const float* __restrict__ mj,
    const float* __restrict__ vj,
    unsigned short* __restrict__ outU, unsigned short* __restrict__ outJ) {
    __shared__ float lds[2][4096];            // 2 x 16KB: [64 rows][64 fp32]
    const float *X, *bias, *gamma, *beta, *mean, *var;
    const unsigned short* Wb; unsigned short* out;
    int M, K, m0;
    if (blockIdx.x < TBU) {
        X = Xu; Wb = Wbu; bias = bu; gamma = gu; beta = beu; mean = mu; var = vu;
        out = outU; M = N_USERS; K = 512; m0 = blockIdx.x * 64;
    } else {
        X = Xj; Wb = Wbj; bias = bj; gamma = gj; beta = bej; mean = mj; var = vj;
        out = outJ; M = N_JOBS; K = 768; m0 = (blockIdx.x - TBU) * 64;
    }
    int tid = threadIdx.x;
    int w = tid >> 6, lane = tid & 63;
    int lrow = lane & 15, lgrp = lane >> 4;
    f32x4 acc[4][2];
    #pragma unroll
    for (int m = 0; m < 4; ++m)
        #pragma unroll
        for (int n = 0; n < 2; ++n) acc[m][n] = (f32x4){0.f, 0.f, 0.f, 0.f};

    const unsigned short* wp[2];
    #pragma unroll
    for (int n = 0; n < 2; ++n)
        wp[n] = Wb + (size_t)(w * 32 + n * 16 + lrow) * K + lgrp * 8;

    auto STAGE = [&](int t, int b) {          // 4 x gl_lds16 per thread
        int k0 = t << 6;
        #pragma unroll
        for (int c = 0; c < 4; ++c) {
            int unit = c * 256 + tid;         // 16B unit index (1024 total)
            int row = unit >> 4, u = unit & 15;
            int gr = m0 + row; if (gr > M - 1) gr = M - 1;
            const float* g = X + (size_t)gr * K + k0 + ((u ^ (row & 15)) << 2);
            gl_lds16(g, (void*)&lds[b][unit * 4]);
        }
    };
    auto LOADW = [&](int t, short8* dst) {    // dst[ks*2+n], W frags for step t
        int k0 = t << 6;
        #pragma unroll
        for (int ks = 0; ks < 2; ++ks)
            #pragma unroll
            for (int n = 0; n < 2; ++n)
                dst[ks * 2 + n] = *reinterpret_cast<const short8*>(wp[n] + k0 + ks * 32);
    };

    int nt = K >> 6;
    short8 bfc[4], bfn[4];
    LOADW(0, bfc);
    STAGE(0, 0);
    __syncthreads();
    for (int t = 0; t < nt; ++t) {
        if (t + 1 < nt) { LOADW(t + 1, bfn); STAGE(t + 1, (t + 1) & 1); }
        const float* bufp = &lds[t & 1][0];
        #pragma unroll
        for (int ks = 0; ks < 2; ++ks) {
            int p = ks * 4 + lgrp;            // logical 32B-pair index
            #pragma unroll
            for (int m = 0; m < 4; ++m) {
                int row = m * 16 + lrow;
                int swz = row & 15;
                float4 ra = *reinterpret_cast<const float4*>(bufp + row * 64 + (((2 * p)     ^ swz) << 2));
                float4 rb = *reinterpret_cast<const float4*>(bufp + row * 64 + (((2 * p + 1) ^ swz) << 2));
                union { unsigned u[4]; short8 s; } r;
                r.u[0] = pk2(ra.x, ra.y); r.u[1] = pk2(ra.z, ra.w);
                r.u[2] = pk2(rb.x, rb.y); r.u[3] = pk2(rb.z, rb.w);
                acc[m][0] = __builtin_amdgcn_mfma_f32_16x16x32_bf16(bfc[ks * 2 + 0], r.s, acc[m][0], 0, 0, 0);
                acc[m][1] = __builtin_amdgcn_mfma_f32_16x16x32_bf16(bfc[ks * 2 + 1], r.s, acc[m][1], 0, 0, 0);
            }
        }
        __syncthreads();
        if (t + 1 < nt) {
            #pragma unroll
            for (int i = 0; i < 4; ++i) bfc[i] = bfn[i];
        }
    }

    // epilogue: lane owns row (m*16+lrow), cols w*32 + n*16 + lgrp*4 + j
    float sc[2][4], sh[2][4];
    #pragma unroll
    for (int n = 0; n < 2; ++n)
        #pragma unroll
        for (int j = 0; j < 4; ++j) {
            int gc = w * 32 + n * 16 + lgrp * 4 + j;
            float s = gamma[gc] * rsqrtf(var[gc] + 1e-5f);
            sc[n][j] = s;
            sh[n][j] = (bias[gc] - mean[gc]) * s + beta[gc];
        }
    #pragma unroll
    for (int m = 0; m < 4; ++m) {
        int row = m0 + m * 16 + lrow;
        if (row < M) {
            #pragma unroll
            for (int n = 0; n < 2; ++n) {
                float v0 = fmaxf(acc[m][n][0] * sc[n][0] + sh[n][0], 0.f);
                float v1 = fmaxf(acc[m][n][1] * sc[n][1] + sh[n][1], 0.f);
                float v2 = fmaxf(acc[m][n][2] * sc[n][2] + sh[n][2], 0.f);
                float v3 = fmaxf(acc[m][n][3] * sc[n][3] + sh[n][3], 0.f);
                *reinterpret_cast<uint2*>(out + (size_t)row * HID + w * 32 + n * 16 + lgrp * 4) =
                    make_uint2(pk2(v0, v1), pk2(v2, v3));
            }
        }
    }
}

// ---------------------------------------------------------------------------
// FUSED SAGE layer (aggregation + dual GEMM, both sides in one launch):
//   out = [relu]( mean_agg(x, CSR) @ WA^T + bl + Bx @ WB^T )
// Each block owns 64 destination nodes: phase 1 gathers/means its 64 CSR rows
// straight into the swizzled LDS A-tile (f32 accum -> bf16, same rounding as
// the old standalone aggregation). Bx is DMA'd via global_load_lds at kernel
// entry (completes under the gather phase). Phase 2: 4 K-steps of MFMA.
// ---------------------------------------------------------------------------
__global__ __launch_bounds__(256) void sage_fused(
    const unsigned short* __restrict__ xJ, const int* __restrict__ offJ,
    const int* __restrict__ valsJ, const unsigned short* __restrict__ BxJ,
    const unsigned short* __restrict__ WAj, const unsigned short* __restrict__ WBj,
    const float* __restrict__ blJ, unsigned short* __restrict__ outJ,
    const unsigned short* __restrict__ xU, const int* __restrict__ offU,
    const int* __restrict__ valsU, const unsigned short* __restrict__ BxU,
    const unsigned short* __restrict__ WAu, const unsigned short* __restrict__ WBu,
    const float* __restrict__ blU, unsigned short* __restrict__ outU,
    int doRelu) {
    __shared__ unsigned short Atile[64 * 128];     // 16KB, swizzled (16 units/row)
    __shared__ unsigned short Bst[2][64 * 64];     // 16KB, swizzled (8 units/row)
    const unsigned short *x, *Bx, *WA, *WB; const int *off, *vals;
    const float* bl; unsigned short* out; int M, m0;
    if (blockIdx.x < TBJ) {
        x = xJ; off = offJ; vals = valsJ; Bx = BxJ; WA = WAj; WB = WBj;
        bl = blJ; out = outJ; M = N_JOBS; m0 = blockIdx.x * 64;
    } else {
        x = xU; off = offU; vals = valsU; Bx = BxU; WA = WAu; WB = WBu;
        bl = blU; out = outU; M = N_USERS; m0 = (blockIdx.x - TBJ) * 64;
    }
    int tid = threadIdx.x;
    int w = tid >> 6, lane = tid & 63;
    int lrow = lane & 15, lgrp = lane >> 4;

    // ---- stage BOTH Bx K-halves up front (async DMA, drains at the barrier)
    #pragma unroll
    for (int c = 0; c < 4; ++c) {
        int q = c * 256 + tid;                // 0..1023 16B units
        int buf = q >> 9;                     // K-half
        int unit = q & 511;
        int row = unit >> 3, u = unit & 7;
        int gr = m0 + row; if (gr > M - 1) gr = M - 1;
        const unsigned short* g = Bx + (size_t)gr * HID + (buf << 6) + ((u ^ (row & 7)) << 3);
        gl_lds16(g, (void*)(&Bst[buf][0] + unit * 8));
    }

    // ---- W fragments for step 0 (hidden under gathers)
    const unsigned short* wrow[2];
    #pragma unroll
    for (int n = 0; n < 2; ++n)
        wrow[n] = (size_t)(w * 32 + n * 16 + lrow) * HID + lgrp * 8 + (const unsigned short*)nullptr + 0;
    // (base added per-step below; keep offsets only)
    size_t woff[2];
    #pragma unroll
    for (int n = 0; n < 2; ++n)
        woff[n] = (size_t)(w * 32 + n * 16 + lrow) * HID + lgrp * 8;
    short8 bfc[4], bfn[4];
    #pragma unroll
    for (int ks = 0; ks < 2; ++ks)
        #pragma unroll
        for (int n = 0; n < 2; ++n)
            bfc[ks * 2 + n] = *reinterpret_cast<const short8*>(WA + woff[n] + ks * 32);

    // ---- phase 1: aggregate this block's 64 nodes into Atile
    int hl = lane & 31;           // feature group (8B = 4 bf16)
    int eo = lane >> 5;           // edge parity within pair
    for (int i = 0; i < 16; ++i) {
        int row = w * 16 + i;
        int node = m0 + row;
        if (node >= M) break;
        int beg = off[node], end = off[node + 1];
        float a0 = 0.f, a1 = 0.f, a2 = 0.f, a3 = 0.f;
        int e = beg;
        for (; e + 7 < end; e += 8) {
            int s0 = vals[e + eo],     s1 = vals[e + 2 + eo];
            int s2 = vals[e + 4 + eo], s3 = vals[e + 6 + eo];
            uint2 v0 = *reinterpret_cast<const uint2*>(x + (size_t)s0 * HID + hl * 4);
            uint2 v1 = *reinterpret_cast<const uint2*>(x + (size_t)s1 * HID + hl * 4);
            uint2 v2 = *reinterpret_cast<const uint2*>(x + (size_t)s2 * HID + hl * 4);
            uint2 v3 = *reinterpret_cast<const uint2*>(x + (size_t)s3 * HID + hl * 4);
            a0 += b2f(v0.x & 0xffffu) + b2f(v1.x & 0xffffu) + b2f(v2.x & 0xffffu) + b2f(v3.x & 0xffffu);
            a1 += b2f(v0.x >> 16)     + b2f(v1.x >> 16)     + b2f(v2.x >> 16)     + b2f(v3.x >> 16);
            a2 += b2f(v0.y & 0xffffu) + b2f(v1.y & 0xffffu) + b2f(v2.y & 0xffffu) + b2f(v3.y & 0xffffu);
            a3 += b2f(v0.y >> 16)     + b2f(v1.y >> 16)     + b2f(v2.y >> 16)     + b2f(v3.y >> 16);
        }
        for (; e < end; e += 2) {
            int ee = e + eo;
            if (ee < end) {
                int s = vals[ee];
                uint2 v = *reinterpret_cast<const uint2*>(x + (size_t)s * HID + hl * 4);
                a0 += b2f(v.x & 0xffffu);
                a1 += b2f(v.x >> 16);
                a2 += b2f(v.y & 0xffffu);
                a3 += b2f(v.y >> 16);
            }
        }
        a0 += __shfl_xor(a0, 32, 64);
        a1 += __shfl_xor(a1, 32, 64);
        a2 += __shfl_xor(a2, 32, 64);
        a3 += __shfl_xor(a3, 32, 64);
        if (eo == 0) {
            float inv = 1.0f / fmaxf((float)(end - beg), 1.0f);
            int su = (hl >> 1) ^ i;           // row&15 == i (w*16 aligned)
            *reinterpret_cast<uint2*>(Atile + row * 128 + su * 8 + (hl & 1) * 4) =
                make_uint2(pk2(a0 * inv, a1 * inv), pk2(a2 * inv, a3 * inv));
        }
    }
    __syncthreads();   // drains Bx DMA too

    // ---- phase 2: 4 K-steps (A k0=0,64 then Bx k0=0,64)
    f32x4 acc[4][2];
    #pragma unroll
    for (int m = 0; m < 4; ++m)
        #pragma unroll
        for (int n = 0; n < 2; ++n) acc[m][n] = (f32x4){0.f, 0.f, 0.f, 0.f};

    #pragma unroll
    for (int s = 0; s < 4; ++s) {
        if (s < 3) {   // prefetch next step's W frags
            const unsigned short* Wn = (s + 1 < 2) ? WA : WB;
            int k0n = ((s + 1) & 1) << 6;
            #pragma unroll
            for (int ks = 0; ks < 2; ++ks)
                #pragma unroll
                for (int n = 0; n < 2; ++n)
                    bfn[ks * 2 + n] = *reinterpret_cast<const short8*>(Wn + woff[n] + k0n + ks * 32);
        }
        #pragma unroll
        for (int ks = 0; ks < 2; ++ks) {
            int p = ks * 4 + lgrp;
            #pragma unroll
            for (int m = 0; m < 4; ++m) {
                int row = m * 16 + lrow;
                short8 af;
                if (s < 2) {
                    int gp = s * 8 + p;       // global 16B unit 0..15
                    af = *reinterpret_cast<const short8*>(Atile + row * 128 + ((gp ^ (row & 15)) * 8));
                } else {
                    af = *reinterpret_cast<const short8*>(&Bst[s & 1][0] + row * 64 + ((p ^ (row & 7)) << 3));
                }
                acc[m][0] = __builtin_amdgcn_mfma_f32_16x16x32_bf16(bfc[ks * 2 + 0], af, acc[m][0], 0, 0, 0);
                acc[m][1] = __builtin_amdgcn_mfma_f32_16x16x32_bf16(bfc[ks * 2 + 1], af, acc[m][1], 0, 0, 0);
            }
        }
        if (s < 3) {
            #pragma unroll
            for (int i = 0; i < 4; ++i) bfc[i] = bfn[i];
        }
    }

    // ---- epilogue: lane owns row (m*16+lrow), cols w*32 + n*16 + lgrp*4 + j
    float blv[2][4];
    #pragma unroll
    for (int n = 0; n < 2; ++n)
        #pragma unroll
        for (int j = 0; j < 4; ++j)
            blv[n][j] = bl[w * 32 + n * 16 + lgrp * 4 + j];
    #pragma unroll
    for (int m = 0; m < 4; ++m) {
        int row = m0 + m * 16 + lrow;
        if (row < M) {
            #pragma unroll
            for (int n = 0; n < 2; ++n) {
                float v[4];
                #pragma unroll
                for (int j = 0; j < 4; ++j) {
                    float xv = acc[m][n][j] + blv[n][j];
                    v[j] = doRelu ? fmaxf(xv, 0.f) : xv;
                }
                *reinterpret_cast<uint2*>(out + (size_t)row * HID + w * 32 + n * 16 + lgrp * 4) =
                    make_uint2(pk2(v[0], v[1]), pk2(v[2], v[3]));
            }
        }
    }
}

// ---------------------------------------------------------------------------
// Link readout: 32 lanes per label edge (2 edges/wave), bf16 inputs (8B/lane),
// fp32 accumulation.
// ---------------------------------------------------------------------------
__global__ __launch_bounds__(256) void dot_kernel(const unsigned short* __restrict__ U,
                                                  const unsigned short* __restrict__ J,
                                                  const int* __restrict__ ls,
                                                  const int* __restrict__ ld,
                                                  float* __restrict__ out, int nL) {
    int ew = (int)((blockIdx.x * blockDim.x + threadIdx.x) >> 5);
    int hl = threadIdx.x & 31;
    if (ew >= nL) return;
    int a = ls[ew], c = ld[ew];
    uint2 uv = *reinterpret_cast<const uint2*>(U + (size_t)a * HID + hl * 4);
    uint2 jv = *reinterpret_cast<const uint2*>(J + (size_t)c * HID + hl * 4);
    float p = b2f(uv.x & 0xffffu) * b2f(jv.x & 0xffffu)
            + b2f(uv.x >> 16)     * b2f(jv.x >> 16)
            + b2f(uv.y & 0xffffu) * b2f(jv.y & 0xffffu)
            + b2f(uv.y >> 16)     * b2f(jv.y >> 16);
    #pragma unroll
    for (int s = 16; s > 0; s >>= 1) p += __shfl_xor(p, s, 64);
    if (hl == 0) out[ew] = p;
}

// ---------------------------------------------------------------------------
extern "C" void kernel_launch(void* const* d_in, const int* in_sizes, int n_in,
                              void* d_out, int out_size, void* d_ws, size_t ws_size,
                              hipStream_t stream) {
    const float* user_x     = (const float*)d_in[0];
    const float* job_x      = (const float*)d_in[1];
    const float* user_W     = (const float*)d_in[2];
    const float* user_b     = (const float*)d_in[3];
    const float* user_gamma = (const float*)d_in[4];
    const float* user_beta  = (const float*)d_in[5];
    const float* user_mean  = (const float*)d_in[6];
    const float* user_var   = (const float*)d_in[7];
    const float* job_W      = (const float*)d_in[8];
    const float* job_b      = (const float*)d_in[9];
    const float* job_gamma  = (const float*)d_in[10];
    const float* job_beta   = (const float*)d_in[11];
    const float* job_mean   = (const float*)d_in[12];
    const float* job_var    = (const float*)d_in[13];
    const float* l1_rates_Wl = (const float*)d_in[14];
    const float* l1_rates_Wr = (const float*)d_in[15];
    const float* l1_rev_Wl   = (const float*)d_in[16];
    const float* l1_rev_Wr   = (const float*)d_in[17];
    const float* l2_rates_Wl = (const float*)d_in[18];
    const float* l2_rates_Wr = (const float*)d_in[19];
    const float* l2_rev_Wl   = (const float*)d_in[20];
    const float* l2_rev_Wr   = (const float*)d_in[21];
    const float* l1_rates_bl = (const float*)d_in[22];
    const float* l1_rev_bl   = (const float*)d_in[23];
    const float* l2_rates_bl = (const float*)d_in[24];
    const float* l2_rev_bl   = (const float*)d_in[25];
    const int* rates_src = (const int*)d_in[26];
    const int* rates_dst = (const int*)d_in[27];
    const int* label_src = (const int*)d_in[28];
    const int* label_dst = (const int*)d_in[29];

    // ---- workspace layout ----
    char* ws = (char*)d_ws;
    size_t o = 0;
    auto alloc = [&](size_t bytes) -> void* {
        void* p = ws + o;
        o = (o + bytes + 511) & ~(size_t)511;
        return p;
    };
    unsigned short* u_bf = (unsigned short*)alloc((size_t)N_USERS * HID * 2);
    unsigned short* j_bf = (unsigned short*)alloc((size_t)N_JOBS  * HID * 2);
    unsigned short* u1   = (unsigned short*)alloc((size_t)N_USERS * HID * 2);
    unsigned short* j1   = (unsigned short*)alloc((size_t)N_JOBS  * HID * 2);
    unsigned short* u2b  = (unsigned short*)alloc((size_t)N_USERS * HID * 2);
    unsigned short* j2b  = (unsigned short*)alloc((size_t)N_JOBS  * HID * 2);
    int* vals_j = (int*)alloc((size_t)N_EDGES * 4);
    int* vals_u = (int*)alloc((size_t)N_EDGES * 4);
    unsigned* stage_j = (unsigned*)alloc((size_t)N_EDGES * 4);
    unsigned* stage_u = (unsigned*)alloc((size_t)N_EDGES * 4);
    int* off_j  = (int*)alloc((size_t)(N_JOBS + 1) * 4);
    int* off_u  = (int*)alloc((size_t)(N_USERS + 1) * 4);
    int* bcnt_j = (int*)alloc((size_t)(NBJ + 1) * 4);
    int* bcnt_u = (int*)alloc((size_t)(NBU + 1) * 4);
    int* boff_j = (int*)alloc((size_t)(NBJ + 1) * 4);
    int* boff_u = (int*)alloc((size_t)(NBU + 1) * 4);
    int* bcur_j = (int*)alloc((size_t)(NBJ + 1) * 4);
    int* bcur_u = (int*)alloc((size_t)(NBU + 1) * 4);
    unsigned short* wbf = (unsigned short*)alloc((size_t)294912 * 2);
    (void)ws_size; (void)n_in; (void)in_sizes; (void)out_size;

    const unsigned short* uWb = wbf;
    const unsigned short* jWb = wbf + 65536;
    const unsigned short* w8  = wbf + 163840;   // 8 x [128][128]

    // ---- weight conversion + bcnt zeroing (once per call, tiny) ----
    cvt_weights<<<289, 256, 0, stream>>>(user_W, job_W,
        l1_rates_Wl, l1_rates_Wr, l1_rev_Wl, l1_rev_Wr,
        l2_rates_Wl, l2_rates_Wr, l2_rev_Wl, l2_rev_Wr, wbf, bcnt_j, bcnt_u);

    // ---- CSR build (binned, shared by both layers) ----
    bucket_hist<<<512, 256, 0, stream>>>(rates_src, rates_dst, N_EDGES, bcnt_j, bcnt_u);
    bucket_scan<<<2, 1024, 0, stream>>>(bcnt_j, boff_j, bcur_j, bcnt_u, boff_u, bcur_u);
    csr_pass1<<<(N_EDGES + P1CHUNK - 1) / P1CHUNK, 256, 0, stream>>>(
        rates_src, rates_dst, N_EDGES, bcur_j, bcur_u, stage_j, stage_u);
    csr_pass2<<<NBJ + NBU, 256, 0, stream>>>(stage_j, boff_j, off_j, vals_j,
                                             stage_u, boff_u, off_u, vals_u);

    // ---- fused encoders ----
    encoder_mfma<<<TBU + TBJ, 256, 0, stream>>>(
        user_x, uWb, user_b, user_gamma, user_beta, user_mean, user_var,
        job_x, jWb, job_b, job_gamma, job_beta, job_mean, job_var,
        u_bf, j_bf);

    // ---- SAGE layer 1 (aggregation fused into GEMM, relu) ----
    sage_fused<<<TBJ + TBU, 256, 0, stream>>>(
        u_bf, off_j, vals_j, j_bf, w8 + 0 * 16384, w8 + 1 * 16384, l1_rates_bl, j1,
        j_bf, off_u, vals_u, u_bf, w8 + 2 * 16384, w8 + 3 * 16384, l1_rev_bl,   u1, 1);

    // ---- SAGE layer 2 (fused, no relu) ----
    sage_fused<<<TBJ + TBU, 256, 0, stream>>>(
        u1, off_j, vals_j, j1, w8 + 4 * 16384, w8 + 5 * 16384, l2_rates_bl, j2b,
        j1, off_u, vals_u, u1, w8 + 6 * 16384, w8 + 7 * 16384, l2_rev_bl,   u2b, 0);

    // ---- link readout (bf16 gathers, fp32 accum) ----
    dot_kernel<<<(N_LABELS * 32 + 255) / 256, 256, 0, stream>>>(
        u2b, j2b, label_src, label_dst, (float*)d_out, N_LABELS);
}

// Round 11
// 722.340 us; speedup vs baseline: 1.0041x; 1.0041x over previous
//
#include <hip/hip_runtime.h>
#include <cstdint>
#include <cstddef>

#define HID 128
#define N_USERS 100000
#define N_JOBS  50000
#define N_EDGES 2000000
#define N_LABELS 500000

#define RBITS 8
#define RSIZE 256
#define NBJ ((N_JOBS  + RSIZE - 1) / RSIZE)   // 196
#define NBU ((N_USERS + RSIZE - 1) / RSIZE)   // 391
#define P1CHUNK 8192

// GEMM tiling (64-row tiles)
#define TBU ((N_USERS + 63) / 64)   // 1563
#define TBJ ((N_JOBS  + 63) / 64)   // 782
// aggregation blocks: 4 waves = 2 nodes x 2 half-rows per block
#define AB2J ((N_JOBS  + 1) / 2)    // 25000
#define AB2U ((N_USERS + 1) / 2)    // 50000

typedef __attribute__((ext_vector_type(8))) short short8;
typedef __attribute__((ext_vector_type(4))) float f32x4;

__device__ __forceinline__ unsigned short f2b(float f) {
    union { float f; unsigned u; } v; v.f = f;
    unsigned r = v.u + 0x7FFFu + ((v.u >> 16) & 1u);   // RNE to bf16
    return (unsigned short)(r >> 16);
}
__device__ __forceinline__ float b2f(unsigned h) {
    union { unsigned u; float f; } v; v.u = h << 16;
    return v.f;
}
__device__ __forceinline__ unsigned pk2(float lo, float hi) {
    return (unsigned)f2b(lo) | ((unsigned)f2b(hi) << 16);
}
// async global->LDS, 16B per lane; LDS dest = wave-uniform base + lane*16
__device__ __forceinline__ void gl_lds16(const void* g, void* l) {
    __builtin_amdgcn_global_load_lds(
        (const __attribute__((address_space(1))) unsigned int*)g,
        (__attribute__((address_space(3))) unsigned int*)l, 16, 0, 0);
}

// ---------------------------------------------------------------------------
// One-shot: convert all 10 weight matrices fp32 -> bf16 into ws.
// Block 288 also zeroes the bucket-count arrays (replaces 2 memsets).
// ---------------------------------------------------------------------------
__global__ __launch_bounds__(256) void cvt_weights(
    const float* __restrict__ uW, const float* __restrict__ jW,
    const float* __restrict__ a, const float* __restrict__ b,
    const float* __restrict__ c, const float* __restrict__ d,
    const float* __restrict__ e, const float* __restrict__ f,
    const float* __restrict__ g, const float* __restrict__ h,
    unsigned short* __restrict__ ow,
    int* __restrict__ bcnt_j, int* __restrict__ bcnt_u) {
    if (blockIdx.x == 288) {   // dedicated zeroing block
        for (int i = threadIdx.x; i <= NBJ; i += 256) bcnt_j[i] = 0;
        for (int i = threadIdx.x; i <= NBU; i += 256) bcnt_u[i] = 0;
        return;
    }
    int i4 = blockIdx.x * 256 + threadIdx.x;   // float4 index
    if (i4 >= 73728) return;                    // 294912 floats total
    int i = i4 * 4;
    const float* src; int base;
    if (i < 65536)       { src = uW; base = 0; }
    else if (i < 163840) { src = jW; base = 65536; }
    else {
        int k = (i - 163840) >> 14;
        const float* s4 = (k < 4) ? ((k < 2) ? (k == 0 ? a : b) : (k == 2 ? c : d))
                                  : ((k < 6) ? (k == 4 ? e : f) : (k == 6 ? g : h));
        src = s4; base = 163840 + (k << 14);
    }
    float4 v = *reinterpret_cast<const float4*>(src + (i - base));
    *reinterpret_cast<uint2*>(ow + i) = make_uint2(pk2(v.x, v.y), pk2(v.z, v.w));
}

// ---------------------------------------------------------------------------
// CSR build stage 1: bucket histogram (both sides), LDS-aggregated
// ---------------------------------------------------------------------------
__global__ __launch_bounds__(256) void bucket_hist(const int* __restrict__ src,
                                                   const int* __restrict__ dst,
                                                   int nE, int* __restrict__ bcnt_j,
                                                   int* __restrict__ bcnt_u) {
    __shared__ int hj[NBJ];
    __shared__ int hu[NBU];
    int t = threadIdx.x;
    for (int i = t; i < NBJ; i += 256) hj[i] = 0;
    for (int i = t; i < NBU; i += 256) hu[i] = 0;
    __syncthreads();
    int i = blockIdx.x * blockDim.x + t;
    int stride = gridDim.x * blockDim.x;
    for (; i < nE; i += stride) {
        atomicAdd(&hj[dst[i] >> RBITS], 1);
        atomicAdd(&hu[src[i] >> RBITS], 1);
    }
    __syncthreads();
    for (int i2 = t; i2 < NBJ; i2 += 256) if (hj[i2]) atomicAdd(&bcnt_j[i2], hj[i2]);
    for (int i2 = t; i2 < NBU; i2 += 256) if (hu[i2]) atomicAdd(&bcnt_u[i2], hu[i2]);
}

// ---------------------------------------------------------------------------
// CSR build stage 2: exclusive scan of bucket counts (one block per side)
// ---------------------------------------------------------------------------
__global__ __launch_bounds__(1024) void bucket_scan(int* __restrict__ bcnt_j, int* __restrict__ boff_j,
                                                    int* __restrict__ bcur_j,
                                                    int* __restrict__ bcnt_u, int* __restrict__ boff_u,
                                                    int* __restrict__ bcur_u) {
    int* bcnt = blockIdx.x ? bcnt_u : bcnt_j;
    int* boff = blockIdx.x ? boff_u : boff_j;
    int* bcur = blockIdx.x ? bcur_u : bcur_j;
    int n = blockIdx.x ? NBU : NBJ;
    __shared__ int sm[1024];
    int t = threadIdx.x;
    int v = (t < n) ? bcnt[t] : 0;
    sm[t] = v;
    __syncthreads();
    for (int d = 1; d < 1024; d <<= 1) {
        int q = (t >= d) ? sm[t - d] : 0;
        __syncthreads();
        sm[t] += q;
        __syncthreads();
    }
    if (t < n) { int e = sm[t] - v; boff[t] = e; bcur[t] = e; }
    if (t == 0) boff[n] = N_EDGES;
}

// ---------------------------------------------------------------------------
// CSR build stage 3: LDS-binned radix partition (bulk-reserved runs)
// ---------------------------------------------------------------------------
__global__ __launch_bounds__(256) void csr_pass1(const int* __restrict__ src,
                                                 const int* __restrict__ dst,
                                                 int nE, int* __restrict__ gcur_j,
                                                 int* __restrict__ gcur_u,
                                                 unsigned* __restrict__ stage_j,
                                                 unsigned* __restrict__ stage_u) {
    __shared__ int cur_j[NBJ];
    __shared__ int cur_u[NBU];
    int t = threadIdx.x;
    int e0 = blockIdx.x * P1CHUNK;
    int e1 = min(e0 + P1CHUNK, nE);
    for (int i = t; i < NBJ; i += 256) cur_j[i] = 0;
    for (int i = t; i < NBU; i += 256) cur_u[i] = 0;
    __syncthreads();
    for (int e = e0 + t; e < e1; e += 256) {
        atomicAdd(&cur_j[dst[e] >> RBITS], 1);
        atomicAdd(&cur_u[src[e] >> RBITS], 1);
    }
    __syncthreads();
    for (int i = t; i < NBJ; i += 256) {
        int c = cur_j[i];
        cur_j[i] = c ? atomicAdd(&gcur_j[i], c) : 0;
    }
    for (int i = t; i < NBU; i += 256) {
        int c = cur_u[i];
        cur_u[i] = c ? atomicAdd(&gcur_u[i], c) : 0;
    }
    __syncthreads();
    for (int e = e0 + t; e < e1; e += 256) {
        int d = dst[e], s = src[e];
        int pj = atomicAdd(&cur_j[d >> RBITS], 1);
        stage_j[pj] = ((unsigned)(d & (RSIZE - 1)) << 24) | (unsigned)s;
        int pu = atomicAdd(&cur_u[s >> RBITS], 1);
        stage_u[pu] = ((unsigned)(s & (RSIZE - 1)) << 24) | (unsigned)d;
    }
}

// ---------------------------------------------------------------------------
// CSR build stage 4: per-bucket reorder (256 nodes/bucket)
// ---------------------------------------------------------------------------
__global__ __launch_bounds__(256) void csr_pass2(
    const unsigned* __restrict__ stage_j, const int* __restrict__ boff_j,
    int* __restrict__ off_j, int* __restrict__ vals_j,
    const unsigned* __restrict__ stage_u, const int* __restrict__ boff_u,
    int* __restrict__ off_u, int* __restrict__ vals_u) {
    __shared__ int cnt[RSIZE];
    __shared__ int sc[RSIZE];
    __shared__ int cur[RSIZE];
    int borig = blockIdx.x, t = threadIdx.x;
    const unsigned* words; const int* boff; int* off; int* vals; int b; int nNodes;
    if (borig < NBJ) { words = stage_j; boff = boff_j; off = off_j; vals = vals_j; b = borig; nNodes = N_JOBS; }
    else             { words = stage_u; boff = boff_u; off = off_u; vals = vals_u; b = borig - NBJ; nNodes = N_USERS; }
    int node0 = b << RBITS;
    int sbeg = boff[b], send = boff[b + 1];
    cnt[t] = 0;
    __syncthreads();
    for (int e = sbeg + t; e < send; e += 256) {
        atomicAdd(&cnt[words[e] >> 24], 1);
    }
    __syncthreads();
    int v = cnt[t];
    sc[t] = v;
    __syncthreads();
    #pragma unroll
    for (int d = 1; d < RSIZE; d <<= 1) {
        int q = (t >= d) ? sc[t - d] : 0;
        __syncthreads();
        sc[t] += q;
        __syncthreads();
    }
    int node = node0 + t;
    if (node < nNodes) {
        int base = sbeg + sc[t] - v;   // exclusive
        off[node] = base;
        cur[t] = base;
    }
    __syncthreads();
    for (int e = sbeg + t; e < send; e += 256) {
        unsigned w = words[e];
        int slot = atomicAdd(&cur[w >> 24], 1);
        vals[slot] = (int)(w & 0xFFFFFFu);
    }
    if (t == 0 && borig == 0)   off_j[N_JOBS]  = N_EDGES;
    if (t == 0 && borig == NBJ) off_u[N_USERS] = N_EDGES;
}

// ---------------------------------------------------------------------------
// FUSED mean aggregation (both sides). One WAVE per (node, half-row):
// 16-lane groups cover a 128B half-row; 4 edges concurrently per instruction
// (eo = lane>>4), 8 in flight with the 2-step unroll. Reduce via shfl_xor
// (16, 32); lanes 0-15 write the 128B half-row.
// ---------------------------------------------------------------------------
__global__ __launch_bounds__(256) void aggregate2(
    const unsigned short* __restrict__ xJ, const int* __restrict__ offJ,
    const int* __restrict__ valsJ, unsigned short* __restrict__ outJ,
    const unsigned short* __restrict__ xU, const int* __restrict__ offU,
    const int* __restrict__ valsU, unsigned short* __restrict__ outU) {
    int bb = blockIdx.x;
    const unsigned short* x; const int* off; const int* vals; unsigned short* out;
    int nDst, node0;
    if (bb < AB2J) { x = xJ; off = offJ; vals = valsJ; out = outJ; nDst = N_JOBS;  node0 = bb * 2; }
    else           { x = xU; off = offU; vals = valsU; out = outU; nDst = N_USERS; node0 = (bb - AB2J) * 2; }
    int wid = threadIdx.x >> 6;
    int node = node0 + (wid >> 1);
    if (node >= nDst) return;
    int half = wid & 1;
    int lane = threadIdx.x & 63;
    int hl = lane & 15;           // 8B feature group within the half-row
    int eo = lane >> 4;           // 0..3: edge slot within quad
    const unsigned short* xb = x + half * 64 + hl * 4;
    int beg = off[node], end = off[node + 1];
    float a0 = 0.f, a1 = 0.f, a2 = 0.f, a3 = 0.f;
    int e = beg;
    for (; e + 7 < end; e += 8) {
        int s0 = vals[e + eo], s1 = vals[e + 4 + eo];
        uint2 v0 = *reinterpret_cast<const uint2*>(xb + (size_t)s0 * HID);
        uint2 v1 = *reinterpret_cast<const uint2*>(xb + (size_t)s1 * HID);
        a0 += b2f(v0.x & 0xffffu) + b2f(v1.x & 0xffffu);
        a1 += b2f(v0.x >> 16)     + b2f(v1.x >> 16);
        a2 += b2f(v0.y & 0xffffu) + b2f(v1.y & 0xffffu);
        a3 += b2f(v0.y >> 16)     + b2f(v1.y >> 16);
    }
    for (; e < end; e += 4) {
        int ee = e + eo;
        if (ee < end) {
            int s = vals[ee];
            uint2 v = *reinterpret_cast<const uint2*>(xb + (size_t)s * HID);
            a0 += b2f(v.x & 0xffffu);
            a1 += b2f(v.x >> 16);
            a2 += b2f(v.y & 0xffffu);
            a3 += b2f(v.y >> 16);
        }
    }
    a0 += __shfl_xor(a0, 16, 64); a0 += __shfl_xor(a0, 32, 64);
    a1 += __shfl_xor(a1, 16, 64); a1 += __shfl_xor(a1, 32, 64);
    a2 += __shfl_xor(a2, 16, 64); a2 += __shfl_xor(a2, 32, 64);
    a3 += __shfl_xor(a3, 16, 64); a3 += __shfl_xor(a3, 32, 64);
    if (eo == 0) {
        float inv = 1.0f / fmaxf((float)(end - beg), 1.0f);
        *reinterpret_cast<uint2*>(out + (size_t)node * HID + half * 64 + hl * 4) =
            make_uint2(pk2(a0 * inv, a1 * inv), pk2(a2 * inv, a3 * inv));
    }
}

// ---------------------------------------------------------------------------
// FUSED encoder (user + job sides): out_bf16 = relu(BN(X @ W^T + b)).
// 64x128 tile, BK=64, async global_load_lds double-buffered X staging with
// 16B-unit XOR swizzle; W fragments prefetched into VGPRs.
// ---------------------------------------------------------------------------
__global__ __launch_bounds__(256) void encoder_mfma(
    const float* __restrict__ Xu, const unsigned short* __restrict__ Wbu,
    const float* __restrict__ bu, const float* __restrict__ gu,
    const float* __restrict__ beu, const float* __restrict__ mu,
    const float* __restrict__ vu,
    const float* __restrict__ Xj, const unsigned short* __restrict__ Wbj,
    const float* __restrict__ bj, const float* __restrict__ gj,
    const float* __restrict__ bej, const float* __restrict__ mj,
    const float* __restrict__ vj,
    unsigned short* __restrict__ outU, unsigned short* __restrict__ outJ) {
    __shared__ float lds[2][4096];            // 2 x 16KB: [64 rows][64 fp32]
    const float *X, *bias, *gamma, *beta, *mean, *var;
    const unsigned short* Wb; unsigned short* out;
    int M, K, m0;
    if (blockIdx.x < TBU) {
        X = Xu; Wb = Wbu; bias = bu; gamma = gu; beta = beu; mean = mu; var = vu;
        out = outU; M = N_USERS; K = 512; m0 = blockIdx.x * 64;
    } else {
        X = Xj; Wb = Wbj; bias = bj; gamma = gj; beta = bej; mean = mj; var = vj;
        out = outJ; M = N_JOBS; K = 768; m0 = (blockIdx.x - TBU) * 64;
    }
    int tid = threadIdx.x;
    int w = tid >> 6, lane = tid & 63;
    int lrow = lane & 15, lgrp = lane >> 4;
    f32x4 acc[4][2];
    #pragma unroll
    for (int m = 0; m < 4; ++m)
        #pragma unroll
        for (int n = 0; n < 2; ++n) acc[m][n] = (f32x4){0.f, 0.f, 0.f, 0.f};

    const unsigned short* wp[2];
    #pragma unroll
    for (int n = 0; n < 2; ++n)
        wp[n] = Wb + (size_t)(w * 32 + n * 16 + lrow) * K + lgrp * 8;

    auto STAGE = [&](int t, int b) {          // 4 x gl_lds16 per thread
        int k0 = t << 6;
        #pragma unroll
        for (int c = 0; c < 4; ++c) {
            int unit = c * 256 + tid;         // 16B unit index (1024 total)
            int row = unit >> 4, u = unit & 15;
            int gr = m0 + row; if (gr > M - 1) gr = M - 1;
            const float* g = X + (size_t)gr * K + k0 + ((u ^ (row & 15)) << 2);
            gl_lds16(g, (void*)&lds[b][unit * 4]);
        }
    };
    auto LOADW = [&](int t, short8* dst) {    // dst[ks*2+n], W frags for step t
        int k0 = t << 6;
        #pragma unroll
        for (int ks = 0; ks < 2; ++ks)
            #pragma unroll
            for (int n = 0; n < 2; ++n)
                dst[ks * 2 + n] = *reinterpret_cast<const short8*>(wp[n] + k0 + ks * 32);
    };

    int nt = K >> 6;
    short8 bfc[4], bfn[4];
    LOADW(0, bfc);
    STAGE(0, 0);
    __syncthreads();
    for (int t = 0; t < nt; ++t) {
        if (t + 1 < nt) { LOADW(t + 1, bfn); STAGE(t + 1, (t + 1) & 1); }
        const float* bufp = &lds[t & 1][0];
        #pragma unroll
        for (int ks = 0; ks < 2; ++ks) {
            int p = ks * 4 + lgrp;            // logical 32B-pair index
            #pragma unroll
            for (int m = 0; m < 4; ++m) {
                int row = m * 16 + lrow;
                int swz = row & 15;
                float4 ra = *reinterpret_cast<const float4*>(bufp + row * 64 + (((2 * p)     ^ swz) << 2));
                float4 rb = *reinterpret_cast<const float4*>(bufp + row * 64 + (((2 * p + 1) ^ swz) << 2));
                union { unsigned u[4]; short8 s; } r;
                r.u[0] = pk2(ra.x, ra.y); r.u[1] = pk2(ra.z, ra.w);
                r.u[2] = pk2(rb.x, rb.y); r.u[3] = pk2(rb.z, rb.w);
                acc[m][0] = __builtin_amdgcn_mfma_f32_16x16x32_bf16(bfc[ks * 2 + 0], r.s, acc[m][0], 0, 0, 0);
                acc[m][1] = __builtin_amdgcn_mfma_f32_16x16x32_bf16(bfc[ks * 2 + 1], r.s, acc[m][1], 0, 0, 0);
            }
        }
        __syncthreads();
        if (t + 1 < nt) {
            #pragma unroll
            for (int i = 0; i < 4; ++i) bfc[i] = bfn[i];
        }
    }

    // epilogue: lane owns row (m*16+lrow), cols w*32 + n*16 + lgrp*4 + j
    float sc[2][4], sh[2][4];
    #pragma unroll
    for (int n = 0; n < 2; ++n)
        #pragma unroll
        for (int j = 0; j < 4; ++j) {
            int gc = w * 32 + n * 16 + lgrp * 4 + j;
            float s = gamma[gc] * rsqrtf(var[gc] + 1e-5f);
            sc[n][j] = s;
            sh[n][j] = (bias[gc] - mean[gc]) * s + beta[gc];
        }
    #pragma unroll
    for (int m = 0; m < 4; ++m) {
        int row = m0 + m * 16 + lrow;
        if (row < M) {
            #pragma unroll
            for (int n = 0; n < 2; ++n) {
                float v0 = fmaxf(acc[m][n][0] * sc[n][0] + sh[n][0], 0.f);
                float v1 = fmaxf(acc[m][n][1] * sc[n][1] + sh[n][1], 0.f);
                float v2 = fmaxf(acc[m][n][2] * sc[n][2] + sh[n][2], 0.f);
                float v3 = fmaxf(acc[m][n][3] * sc[n][3] + sh[n][3], 0.f);
                *reinterpret_cast<uint2*>(out + (size_t)row * HID + w * 32 + n * 16 + lgrp * 4) =
                    make_uint2(pk2(v0, v1), pk2(v2, v3));
            }
        }
    }
}

// ---------------------------------------------------------------------------
// FUSED SAGE dual GEMM (both sides): out = [relu](Aagg @ WA^T + bl + Bx @ WB^T)
// All operands bf16; async-staged double-buffered LDS; bf16 output.
// ---------------------------------------------------------------------------
__global__ __launch_bounds__(256) void sage_mfma(
    const unsigned short* __restrict__ AaggJ, const unsigned short* __restrict__ BxJ,
    const unsigned short* __restrict__ WAj, const unsigned short* __restrict__ WBj,
    const float* __restrict__ blJ, unsigned short* __restrict__ outJ,
    const unsigned short* __restrict__ AaggU, const unsigned short* __restrict__ BxU,
    const unsigned short* __restrict__ WAu, const unsigned short* __restrict__ WBu,
    const float* __restrict__ blU, unsigned short* __restrict__ outU,
    int doRelu) {
    __shared__ unsigned short lds[2][4096];   // 2 x 8KB: [64 rows][64 bf16]
    const unsigned short *Aagg, *Bx, *WA, *WB; const float* bl; unsigned short* out;
    int M, m0;
    if (blockIdx.x < TBJ) {
        Aagg = AaggJ; Bx = BxJ; WA = WAj; WB = WBj; bl = blJ; out = outJ;
        M = N_JOBS; m0 = blockIdx.x * 64;
    } else {
        Aagg = AaggU; Bx = BxU; WA = WAu; WB = WBu; bl = blU; out = outU;
        M = N_USERS; m0 = (blockIdx.x - TBJ) * 64;
    }
    int tid = threadIdx.x;
    int w = tid >> 6, lane = tid & 63;
    int lrow = lane & 15, lgrp = lane >> 4;
    f32x4 acc[4][2];
    #pragma unroll
    for (int m = 0; m < 4; ++m)
        #pragma unroll
        for (int n = 0; n < 2; ++n) acc[m][n] = (f32x4){0.f, 0.f, 0.f, 0.f};

    auto STAGE = [&](int s, int b) {          // 2 x gl_lds16 per thread
        const unsigned short* Ap = (s < 2) ? Aagg : Bx;
        int k0 = (s & 1) << 6;
        #pragma unroll
        for (int c = 0; c < 2; ++c) {
            int unit = c * 256 + tid;         // 16B unit (512 total)
            int row = unit >> 3, u = unit & 7;
            int gr = m0 + row; if (gr > M - 1) gr = M - 1;
            const unsigned short* g = Ap + (size_t)gr * HID + k0 + ((u ^ (row & 7)) << 3);
            gl_lds16(g, (void*)&lds[b][unit * 8]);
        }
    };
    auto LOADW = [&](int s, short8* dst) {
        const unsigned short* Wp = (s < 2) ? WA : WB;
        int k0 = (s & 1) << 6;
        #pragma unroll
        for (int ks = 0; ks < 2; ++ks)
            #pragma unroll
            for (int n = 0; n < 2; ++n)
                dst[ks * 2 + n] = *reinterpret_cast<const short8*>(
                    Wp + (size_t)(w * 32 + n * 16 + lrow) * HID + k0 + ks * 32 + lgrp * 8);
    };

    short8 bfc[4], bfn[4];
    LOADW(0, bfc);
    STAGE(0, 0);
    __syncthreads();
    #pragma unroll
    for (int s = 0; s < 4; ++s) {
        if (s < 3) { LOADW(s + 1, bfn); STAGE(s + 1, (s + 1) & 1); }
        const unsigned short* bufp = &lds[s & 1][0];
        #pragma unroll
        for (int ks = 0; ks < 2; ++ks) {
            int p = ks * 4 + lgrp;
            #pragma unroll
            for (int m = 0; m < 4; ++m) {
                int row = m * 16 + lrow;
                short8 af = *reinterpret_cast<const short8*>(bufp + row * 64 + ((p ^ (row & 7)) << 3));
                acc[m][0] = __builtin_amdgcn_mfma_f32_16x16x32_bf16(bfc[ks * 2 + 0], af, acc[m][0], 0, 0, 0);
                acc[m][1] = __builtin_amdgcn_mfma_f32_16x16x32_bf16(bfc[ks * 2 + 1], af, acc[m][1], 0, 0, 0);
            }
        }
        __syncthreads();
        if (s < 3) {
            #pragma unroll
            for (int i = 0; i < 4; ++i) bfc[i] = bfn[i];
        }
    }

    // epilogue: lane owns row (m*16+lrow), cols w*32 + n*16 + lgrp*4 + j
    float blv[2][4];
    #pragma unroll
    for (int n = 0; n < 2; ++n)
        #pragma unroll
        for (int j = 0; j < 4; ++j)
            blv[n][j] = bl[w * 32 + n * 16 + lgrp * 4 + j];
    #pragma unroll
    for (int m = 0; m < 4; ++m) {
        int row = m0 + m * 16 + lrow;
        if (row < M) {
            #pragma unroll
            for (int n = 0; n < 2; ++n) {
                float v[4];
                #pragma unroll
                for (int j = 0; j < 4; ++j) {
                    float x = acc[m][n][j] + blv[n][j];
                    v[j] = doRelu ? fmaxf(x, 0.f) : x;
                }
                *reinterpret_cast<uint2*>(out + (size_t)row * HID + w * 32 + n * 16 + lgrp * 4) =
                    make_uint2(pk2(v[0], v[1]), pk2(v[2], v[3]));
            }
        }
    }
}

// ---------------------------------------------------------------------------
// Link readout: 32 lanes per label edge (2 edges/wave), bf16 inputs (8B/lane),
// fp32 accumulation.
// ---------------------------------------------------------------------------
__global__ __launch_bounds__(256) void dot_kernel(const unsigned short* __restrict__ U,
                                                  const unsigned short* __restrict__ J,
                                                  const int* __restrict__ ls,
                                                  const int* __restrict__ ld,
                                                  float* __restrict__ out, int nL) {
    int ew = (int)((blockIdx.x * blockDim.x + threadIdx.x) >> 5);
    int hl = threadIdx.x & 31;
    if (ew >= nL) return;
    int a = ls[ew], c = ld[ew];
    uint2 uv = *reinterpret_cast<const uint2*>(U + (size_t)a * HID + hl * 4);
    uint2 jv = *reinterpret_cast<const uint2*>(J + (size_t)c * HID + hl * 4);
    float p = b2f(uv.x & 0xffffu) * b2f(jv.x & 0xffffu)
            + b2f(uv.x >> 16)     * b2f(jv.x >> 16)
            + b2f(uv.y & 0xffffu) * b2f(jv.y & 0xffffu)
            + b2f(uv.y >> 16)     * b2f(jv.y >> 16);
    #pragma unroll
    for (int s = 16; s > 0; s >>= 1) p += __shfl_xor(p, s, 64);
    if (hl == 0) out[ew] = p;
}

// ---------------------------------------------------------------------------
extern "C" void kernel_launch(void* const* d_in, const int* in_sizes, int n_in,
                              void* d_out, int out_size, void* d_ws, size_t ws_size,
                              hipStream_t stream) {
    const float* user_x     = (const float*)d_in[0];
    const float* job_x      = (const float*)d_in[1];
    const float* user_W     = (const float*)d_in[2];
    const float* user_b     = (const float*)d_in[3];
    const float* user_gamma = (const float*)d_in[4];
    const float* user_beta  = (const float*)d_in[5];
    const float* user_mean  = (const float*)d_in[6];
    const float* user_var   = (const float*)d_in[7];
    const float* job_W      = (const float*)d_in[8];
    const float* job_b      = (const float*)d_in[9];
    const float* job_gamma  = (const float*)d_in[10];
    const float* job_beta   = (const float*)d_in[11];
    const float* job_mean   = (const float*)d_in[12];
    const float* job_var    = (const float*)d_in[13];
    const float* l1_rates_Wl = (const float*)d_in[14];
    const float* l1_rates_Wr = (const float*)d_in[15];
    const float* l1_rev_Wl   = (const float*)d_in[16];
    const float* l1_rev_Wr   = (const float*)d_in[17];
    const float* l2_rates_Wl = (const float*)d_in[18];
    const float* l2_rates_Wr = (const float*)d_in[19];
    const float* l2_rev_Wl   = (const float*)d_in[20];
    const float* l2_rev_Wr   = (const float*)d_in[21];
    const float* l1_rates_bl = (const float*)d_in[22];
    const float* l1_rev_bl   = (const float*)d_in[23];
    const float* l2_rates_bl = (const float*)d_in[24];
    const float* l2_rev_bl   = (const float*)d_in[25];
    const int* rates_src = (const int*)d_in[26];
    const int* rates_dst = (const int*)d_in[27];
    const int* label_src = (const int*)d_in[28];
    const int* label_dst = (const int*)d_in[29];

    // ---- workspace layout ----
    char* ws = (char*)d_ws;
    size_t o = 0;
    auto alloc = [&](size_t bytes) -> void* {
        void* p = ws + o;
        o = (o + bytes + 511) & ~(size_t)511;
        return p;
    };
    unsigned short* u_bf = (unsigned short*)alloc((size_t)N_USERS * HID * 2);
    unsigned short* j_bf = (unsigned short*)alloc((size_t)N_JOBS  * HID * 2);
    unsigned short* u1   = (unsigned short*)alloc((size_t)N_USERS * HID * 2);
    unsigned short* j1   = (unsigned short*)alloc((size_t)N_JOBS  * HID * 2);
    unsigned short* aggU = (unsigned short*)alloc((size_t)N_USERS * HID * 2);
    unsigned short* aggJ = (unsigned short*)alloc((size_t)N_JOBS  * HID * 2);
    unsigned short* u2b  = (unsigned short*)alloc((size_t)N_USERS * HID * 2);
    unsigned short* j2b  = (unsigned short*)alloc((size_t)N_JOBS  * HID * 2);
    int* vals_j = (int*)alloc((size_t)N_EDGES * 4);
    int* vals_u = (int*)alloc((size_t)N_EDGES * 4);
    unsigned* stage_j = (unsigned*)alloc((size_t)N_EDGES * 4);
    unsigned* stage_u = (unsigned*)alloc((size_t)N_EDGES * 4);
    int* off_j  = (int*)alloc((size_t)(N_JOBS + 1) * 4);
    int* off_u  = (int*)alloc((size_t)(N_USERS + 1) * 4);
    int* bcnt_j = (int*)alloc((size_t)(NBJ + 1) * 4);
    int* bcnt_u = (int*)alloc((size_t)(NBU + 1) * 4);
    int* boff_j = (int*)alloc((size_t)(NBJ + 1) * 4);
    int* boff_u = (int*)alloc((size_t)(NBU + 1) * 4);
    int* bcur_j = (int*)alloc((size_t)(NBJ + 1) * 4);
    int* bcur_u = (int*)alloc((size_t)(NBU + 1) * 4);
    unsigned short* wbf = (unsigned short*)alloc((size_t)294912 * 2);
    (void)ws_size; (void)n_in; (void)in_sizes; (void)out_size;

    const unsigned short* uWb = wbf;
    const unsigned short* jWb = wbf + 65536;
    const unsigned short* w8  = wbf + 163840;   // 8 x [128][128]

    // ---- weight conversion + bcnt zeroing (once per call, tiny) ----
    cvt_weights<<<289, 256, 0, stream>>>(user_W, job_W,
        l1_rates_Wl, l1_rates_Wr, l1_rev_Wl, l1_rev_Wr,
        l2_rates_Wl, l2_rates_Wr, l2_rev_Wl, l2_rev_Wr, wbf, bcnt_j, bcnt_u);

    // ---- CSR build (binned, shared by both layers) ----
    bucket_hist<<<512, 256, 0, stream>>>(rates_src, rates_dst, N_EDGES, bcnt_j, bcnt_u);
    bucket_scan<<<2, 1024, 0, stream>>>(bcnt_j, boff_j, bcur_j, bcnt_u, boff_u, bcur_u);
    csr_pass1<<<(N_EDGES + P1CHUNK - 1) / P1CHUNK, 256, 0, stream>>>(
        rates_src, rates_dst, N_EDGES, bcur_j, bcur_u, stage_j, stage_u);
    csr_pass2<<<NBJ + NBU, 256, 0, stream>>>(stage_j, boff_j, off_j, vals_j,
                                             stage_u, boff_u, off_u, vals_u);

    // ---- fused encoders ----
    encoder_mfma<<<TBU + TBJ, 256, 0, stream>>>(
        user_x, uWb, user_b, user_gamma, user_beta, user_mean, user_var,
        job_x, jWb, job_b, job_gamma, job_beta, job_mean, job_var,
        u_bf, j_bf);

    // ---- SAGE layer 1 (fused aggregation, fused GEMM, relu) ----
    aggregate2<<<AB2J + AB2U, 256, 0, stream>>>(u_bf, off_j, vals_j, aggJ,
                                                j_bf, off_u, vals_u, aggU);
    sage_mfma<<<TBJ + TBU, 256, 0, stream>>>(
        aggJ, j_bf, w8 + 0 * 16384, w8 + 1 * 16384, l1_rates_bl, j1,
        aggU, u_bf, w8 + 2 * 16384, w8 + 3 * 16384, l1_rev_bl,   u1, 1);

    // ---- SAGE layer 2 (fused, no relu, bf16 out) ----
    aggregate2<<<AB2J + AB2U, 256, 0, stream>>>(u1, off_j, vals_j, aggJ,
                                                j1, off_u, vals_u, aggU);
    sage_mfma<<<TBJ + TBU, 256, 0, stream>>>(
        aggJ, j1, w8 + 4 * 16384, w8 + 5 * 16384, l2_rates_bl, j2b,
        aggU, u1, w8 + 6 * 16384, w8 + 7 * 16384, l2_rev_bl,   u2b, 0);

    // ---- link readout (bf16 gathers, fp32 accum) ----
    dot_kernel<<<(N_LABELS * 32 + 255) / 256, 256, 0, stream>>>(
        u2b, j2b, label_src, label_dst, (float*)d_out, N_LABELS);
}

// Round 12
// 586.863 us; speedup vs baseline: 1.2359x; 1.2308x over previous
//
#include <hip/hip_runtime.h>
#include <cstdint>
#include <cstddef>

#define HID 128
#define N_USERS 100000
#define N_JOBS  50000
#define N_EDGES 2000000
#define N_LABELS 500000

#define RBITS 8
#define RSIZE 256
#define NBJ ((N_JOBS  + RSIZE - 1) / RSIZE)   // 196
#define NBU ((N_USERS + RSIZE - 1) / RSIZE)   // 391
#define P1CHUNK 8192

// GEMM tiling (64-row tiles)
#define TBU ((N_USERS + 63) / 64)   // 1563
#define TBJ ((N_JOBS  + 63) / 64)   // 782
// aggregation blocks (4 nodes per 256-thread block)
#define ABJ ((N_JOBS  + 3) / 4)     // 12500
#define ABU ((N_USERS + 3) / 4)     // 25000

typedef __attribute__((ext_vector_type(8))) short short8;
typedef __attribute__((ext_vector_type(4))) float f32x4;

__device__ __forceinline__ unsigned short f2b(float f) {
    union { float f; unsigned u; } v; v.f = f;
    unsigned r = v.u + 0x7FFFu + ((v.u >> 16) & 1u);   // RNE to bf16
    return (unsigned short)(r >> 16);
}
__device__ __forceinline__ float b2f(unsigned h) {
    union { unsigned u; float f; } v; v.u = h << 16;
    return v.f;
}
__device__ __forceinline__ unsigned pk2(float lo, float hi) {
    return (unsigned)f2b(lo) | ((unsigned)f2b(hi) << 16);
}
// async global->LDS, 16B per lane; LDS dest = wave-uniform base + lane*16
__device__ __forceinline__ void gl_lds16(const void* g, void* l) {
    __builtin_amdgcn_global_load_lds(
        (const __attribute__((address_space(1))) unsigned int*)g,
        (__attribute__((address_space(3))) unsigned int*)l, 16, 0, 0);
}

// ---------------------------------------------------------------------------
// One-shot: convert all 10 weight matrices fp32 -> bf16 into ws.
// Block 288 also zeroes the bucket-count arrays (replaces 2 memsets).
// ---------------------------------------------------------------------------
__global__ __launch_bounds__(256) void cvt_weights(
    const float* __restrict__ uW, const float* __restrict__ jW,
    const float* __restrict__ a, const float* __restrict__ b,
    const float* __restrict__ c, const float* __restrict__ d,
    const float* __restrict__ e, const float* __restrict__ f,
    const float* __restrict__ g, const float* __restrict__ h,
    unsigned short* __restrict__ ow,
    int* __restrict__ bcnt_j, int* __restrict__ bcnt_u) {
    if (blockIdx.x == 288) {   // dedicated zeroing block
        for (int i = threadIdx.x; i <= NBJ; i += 256) bcnt_j[i] = 0;
        for (int i = threadIdx.x; i <= NBU; i += 256) bcnt_u[i] = 0;
        return;
    }
    int i4 = blockIdx.x * 256 + threadIdx.x;   // float4 index
    if (i4 >= 73728) return;                    // 294912 floats total
    int i = i4 * 4;
    const float* src; int base;
    if (i < 65536)       { src = uW; base = 0; }
    else if (i < 163840) { src = jW; base = 65536; }
    else {
        int k = (i - 163840) >> 14;
        const float* s4 = (k < 4) ? ((k < 2) ? (k == 0 ? a : b) : (k == 2 ? c : d))
                                  : ((k < 6) ? (k == 4 ? e : f) : (k == 6 ? g : h));
        src = s4; base = 163840 + (k << 14);
    }
    float4 v = *reinterpret_cast<const float4*>(src + (i - base));
    *reinterpret_cast<uint2*>(ow + i) = make_uint2(pk2(v.x, v.y), pk2(v.z, v.w));
}

// ---------------------------------------------------------------------------
// CSR build stage 1: bucket histogram (both sides), LDS-aggregated
// ---------------------------------------------------------------------------
__global__ __launch_bounds__(256) void bucket_hist(const int* __restrict__ src,
                                                   const int* __restrict__ dst,
                                                   int nE, int* __restrict__ bcnt_j,
                                                   int* __restrict__ bcnt_u) {
    __shared__ int hj[NBJ];
    __shared__ int hu[NBU];
    int t = threadIdx.x;
    for (int i = t; i < NBJ; i += 256) hj[i] = 0;
    for (int i = t; i < NBU; i += 256) hu[i] = 0;
    __syncthreads();
    int i = blockIdx.x * blockDim.x + t;
    int stride = gridDim.x * blockDim.x;
    for (; i < nE; i += stride) {
        atomicAdd(&hj[dst[i] >> RBITS], 1);
        atomicAdd(&hu[src[i] >> RBITS], 1);
    }
    __syncthreads();
    for (int i2 = t; i2 < NBJ; i2 += 256) if (hj[i2]) atomicAdd(&bcnt_j[i2], hj[i2]);
    for (int i2 = t; i2 < NBU; i2 += 256) if (hu[i2]) atomicAdd(&bcnt_u[i2], hu[i2]);
}

// ---------------------------------------------------------------------------
// CSR build stage 2: exclusive scan of bucket counts (one block per side)
// ---------------------------------------------------------------------------
__global__ __launch_bounds__(1024) void bucket_scan(int* __restrict__ bcnt_j, int* __restrict__ boff_j,
                                                    int* __restrict__ bcur_j,
                                                    int* __restrict__ bcnt_u, int* __restrict__ boff_u,
                                                    int* __restrict__ bcur_u) {
    int* bcnt = blockIdx.x ? bcnt_u : bcnt_j;
    int* boff = blockIdx.x ? boff_u : boff_j;
    int* bcur = blockIdx.x ? bcur_u : bcur_j;
    int n = blockIdx.x ? NBU : NBJ;
    __shared__ int sm[1024];
    int t = threadIdx.x;
    int v = (t < n) ? bcnt[t] : 0;
    sm[t] = v;
    __syncthreads();
    for (int d = 1; d < 1024; d <<= 1) {
        int q = (t >= d) ? sm[t - d] : 0;
        __syncthreads();
        sm[t] += q;
        __syncthreads();
    }
    if (t < n) { int e = sm[t] - v; boff[t] = e; bcur[t] = e; }
    if (t == 0) boff[n] = N_EDGES;
}

// ---------------------------------------------------------------------------
// CSR build stage 3: LDS-binned radix partition (bulk-reserved runs)
// ---------------------------------------------------------------------------
__global__ __launch_bounds__(256) void csr_pass1(const int* __restrict__ src,
                                                 const int* __restrict__ dst,
                                                 int nE, int* __restrict__ gcur_j,
                                                 int* __restrict__ gcur_u,
                                                 unsigned* __restrict__ stage_j,
                                                 unsigned* __restrict__ stage_u) {
    __shared__ int cur_j[NBJ];
    __shared__ int cur_u[NBU];
    int t = threadIdx.x;
    int e0 = blockIdx.x * P1CHUNK;
    int e1 = min(e0 + P1CHUNK, nE);
    for (int i = t; i < NBJ; i += 256) cur_j[i] = 0;
    for (int i = t; i < NBU; i += 256) cur_u[i] = 0;
    __syncthreads();
    for (int e = e0 + t; e < e1; e += 256) {
        atomicAdd(&cur_j[dst[e] >> RBITS], 1);
        atomicAdd(&cur_u[src[e] >> RBITS], 1);
    }
    __syncthreads();
    for (int i = t; i < NBJ; i += 256) {
        int c = cur_j[i];
        cur_j[i] = c ? atomicAdd(&gcur_j[i], c) : 0;
    }
    for (int i = t; i < NBU; i += 256) {
        int c = cur_u[i];
        cur_u[i] = c ? atomicAdd(&gcur_u[i], c) : 0;
    }
    __syncthreads();
    for (int e = e0 + t; e < e1; e += 256) {
        int d = dst[e], s = src[e];
        int pj = atomicAdd(&cur_j[d >> RBITS], 1);
        stage_j[pj] = ((unsigned)(d & (RSIZE - 1)) << 24) | (unsigned)s;
        int pu = atomicAdd(&cur_u[s >> RBITS], 1);
        stage_u[pu] = ((unsigned)(s & (RSIZE - 1)) << 24) | (unsigned)d;
    }
}

// ---------------------------------------------------------------------------
// CSR build stage 4: per-bucket reorder (256 nodes/bucket)
// ---------------------------------------------------------------------------
__global__ __launch_bounds__(256) void csr_pass2(
    const unsigned* __restrict__ stage_j, const int* __restrict__ boff_j,
    int* __restrict__ off_j, int* __restrict__ vals_j,
    const unsigned* __restrict__ stage_u, const int* __restrict__ boff_u,
    int* __restrict__ off_u, int* __restrict__ vals_u) {
    __shared__ int cnt[RSIZE];
    __shared__ int sc[RSIZE];
    __shared__ int cur[RSIZE];
    int borig = blockIdx.x, t = threadIdx.x;
    const unsigned* words; const int* boff; int* off; int* vals; int b; int nNodes;
    if (borig < NBJ) { words = stage_j; boff = boff_j; off = off_j; vals = vals_j; b = borig; nNodes = N_JOBS; }
    else             { words = stage_u; boff = boff_u; off = off_u; vals = vals_u; b = borig - NBJ; nNodes = N_USERS; }
    int node0 = b << RBITS;
    int sbeg = boff[b], send = boff[b + 1];
    cnt[t] = 0;
    __syncthreads();
    for (int e = sbeg + t; e < send; e += 256) {
        atomicAdd(&cnt[words[e] >> 24], 1);
    }
    __syncthreads();
    int v = cnt[t];
    sc[t] = v;
    __syncthreads();
    #pragma unroll
    for (int d = 1; d < RSIZE; d <<= 1) {
        int q = (t >= d) ? sc[t - d] : 0;
        __syncthreads();
        sc[t] += q;
        __syncthreads();
    }
    int node = node0 + t;
    if (node < nNodes) {
        int base = sbeg + sc[t] - v;   // exclusive
        off[node] = base;
        cur[t] = base;
    }
    __syncthreads();
    for (int e = sbeg + t; e < send; e += 256) {
        unsigned w = words[e];
        int slot = atomicAdd(&cur[w >> 24], 1);
        vals[slot] = (int)(w & 0xFFFFFFu);
    }
    if (t == 0 && borig == 0)   off_j[N_JOBS]  = N_EDGES;
    if (t == 0 && borig == NBJ) off_u[N_USERS] = N_EDGES;
}

// ---------------------------------------------------------------------------
// FUSED mean aggregation (both sides in one launch). One wave per node;
// the two 32-lane halves process edges e and e+1 concurrently (8B loads);
// 4-pair unroll -> 8 edges in flight; combined via shfl_xor(32) at the end.
// ---------------------------------------------------------------------------
__global__ __launch_bounds__(256) void aggregate2(
    const unsigned short* __restrict__ xJ, const int* __restrict__ offJ,
    const int* __restrict__ valsJ, unsigned short* __restrict__ outJ,
    const unsigned short* __restrict__ xU, const int* __restrict__ offU,
    const int* __restrict__ valsU, unsigned short* __restrict__ outU) {
    int bb = blockIdx.x;
    const unsigned short* x; const int* off; const int* vals; unsigned short* out;
    int nDst, node0;
    if (bb < ABJ) { x = xJ; off = offJ; vals = valsJ; out = outJ; nDst = N_JOBS;  node0 = bb * 4; }
    else          { x = xU; off = offU; vals = valsU; out = outU; nDst = N_USERS; node0 = (bb - ABJ) * 4; }
    int node = node0 + (threadIdx.x >> 6);
    if (node >= nDst) return;
    int lane = threadIdx.x & 63;
    int hl = lane & 31;           // half-lane: feature group (8B)
    int eo = lane >> 5;           // which edge of the pair
    const unsigned short* xb = x + hl * 4;
    int beg = off[node], end = off[node + 1];
    float a0 = 0.f, a1 = 0.f, a2 = 0.f, a3 = 0.f;
    int e = beg;
    for (; e + 7 < end; e += 8) {
        int s0 = vals[e + eo],     s1 = vals[e + 2 + eo];
        int s2 = vals[e + 4 + eo], s3 = vals[e + 6 + eo];
        uint2 v0 = *reinterpret_cast<const uint2*>(xb + (size_t)s0 * HID);
        uint2 v1 = *reinterpret_cast<const uint2*>(xb + (size_t)s1 * HID);
        uint2 v2 = *reinterpret_cast<const uint2*>(xb + (size_t)s2 * HID);
        uint2 v3 = *reinterpret_cast<const uint2*>(xb + (size_t)s3 * HID);
        a0 += b2f(v0.x & 0xffffu) + b2f(v1.x & 0xffffu) + b2f(v2.x & 0xffffu) + b2f(v3.x & 0xffffu);
        a1 += b2f(v0.x >> 16)     + b2f(v1.x >> 16)     + b2f(v2.x >> 16)     + b2f(v3.x >> 16);
        a2 += b2f(v0.y & 0xffffu) + b2f(v1.y & 0xffffu) + b2f(v2.y & 0xffffu) + b2f(v3.y & 0xffffu);
        a3 += b2f(v0.y >> 16)     + b2f(v1.y >> 16)     + b2f(v2.y >> 16)     + b2f(v3.y >> 16);
    }
    for (; e < end; e += 2) {
        int ee = e + eo;
        if (ee < end) {
            int s = vals[ee];
            uint2 v = *reinterpret_cast<const uint2*>(xb + (size_t)s * HID);
            a0 += b2f(v.x & 0xffffu);
            a1 += b2f(v.x >> 16);
            a2 += b2f(v.y & 0xffffu);
            a3 += b2f(v.y >> 16);
        }
    }
    a0 += __shfl_xor(a0, 32, 64);
    a1 += __shfl_xor(a1, 32, 64);
    a2 += __shfl_xor(a2, 32, 64);
    a3 += __shfl_xor(a3, 32, 64);
    if (eo == 0) {
        float inv = 1.0f / fmaxf((float)(end - beg), 1.0f);
        *reinterpret_cast<uint2*>(out + (size_t)node * HID + hl * 4) =
            make_uint2(pk2(a0 * inv, a1 * inv), pk2(a2 * inv, a3 * inv));
    }
}

// ---------------------------------------------------------------------------
// FUSED encoder (user + job sides): out_bf16 = relu(BN(X @ W^T + b)).
// 64x128 tile, BK=64, async global_load_lds double-buffered X staging with
// 16B-unit XOR swizzle; W fragments prefetched into VGPRs.
// ---------------------------------------------------------------------------
__global__ __launch_bounds__(256) void encoder_mfma(
    const float* __restrict__ Xu, const unsigned short* __restrict__ Wbu,
    const float* __restrict__ bu, const float* __restrict__ gu,
    const float* __restrict__ beu, const float* __restrict__ mu,
    const float* __restrict__ vu,
    const float* __restrict__ Xj, const unsigned short* __restrict__ Wbj,
    const float* __restrict__ bj, const float* __restrict__ gj,
    const float* __restrict__ bej, const float* __restrict__ mj,
    const float* __restrict__ vj,
    unsigned short* __restrict__ outU, unsigned short* __restrict__ outJ) {
    __shared__ float lds[2][4096];            // 2 x 16KB: [64 rows][64 fp32]
    const float *X, *bias, *gamma, *beta, *mean, *var;
    const unsigned short* Wb; unsigned short* out;
    int M, K, m0;
    if (blockIdx.x < TBU) {
        X = Xu; Wb = Wbu; bias = bu; gamma = gu; beta = beu; mean = mu; var = vu;
        out = outU; M = N_USERS; K = 512; m0 = blockIdx.x * 64;
    } else {
        X = Xj; Wb = Wbj; bias = bj; gamma = gj; beta = bej; mean = mj; var = vj;
        out = outJ; M = N_JOBS; K = 768; m0 = (blockIdx.x - TBU) * 64;
    }
    int tid = threadIdx.x;
    int w = tid >> 6, lane = tid & 63;
    int lrow = lane & 15, lgrp = lane >> 4;
    f32x4 acc[4][2];
    #pragma unroll
    for (int m = 0; m < 4; ++m)
        #pragma unroll
        for (int n = 0; n < 2; ++n) acc[m][n] = (f32x4){0.f, 0.f, 0.f, 0.f};

    const unsigned short* wp[2];
    #pragma unroll
    for (int n = 0; n < 2; ++n)
        wp[n] = Wb + (size_t)(w * 32 + n * 16 + lrow) * K + lgrp * 8;

    auto STAGE = [&](int t, int b) {          // 4 x gl_lds16 per thread
        int k0 = t << 6;
        #pragma unroll
        for (int c = 0; c < 4; ++c) {
            int unit = c * 256 + tid;         // 16B unit index (1024 total)
            int row = unit >> 4, u = unit & 15;
            int gr = m0 + row; if (gr > M - 1) gr = M - 1;
            const float* g = X + (size_t)gr * K + k0 + ((u ^ (row & 15)) << 2);
            gl_lds16(g, (void*)&lds[b][unit * 4]);
        }
    };
    auto LOADW = [&](int t, short8* dst) {    // dst[ks*2+n], W frags for step t
        int k0 = t << 6;
        #pragma unroll
        for (int ks = 0; ks < 2; ++ks)
            #pragma unroll
            for (int n = 0; n < 2; ++n)
                dst[ks * 2 + n] = *reinterpret_cast<const short8*>(wp[n] + k0 + ks * 32);
    };

    int nt = K >> 6;
    short8 bfc[4], bfn[4];
    LOADW(0, bfc);
    STAGE(0, 0);
    __syncthreads();
    for (int t = 0; t < nt; ++t) {
        if (t + 1 < nt) { LOADW(t + 1, bfn); STAGE(t + 1, (t + 1) & 1); }
        const float* bufp = &lds[t & 1][0];
        #pragma unroll
        for (int ks = 0; ks < 2; ++ks) {
            int p = ks * 4 + lgrp;            // logical 32B-pair index
            #pragma unroll
            for (int m = 0; m < 4; ++m) {
                int row = m * 16 + lrow;
                int swz = row & 15;
                float4 ra = *reinterpret_cast<const float4*>(bufp + row * 64 + (((2 * p)     ^ swz) << 2));
                float4 rb = *reinterpret_cast<const float4*>(bufp + row * 64 + (((2 * p + 1) ^ swz) << 2));
                union { unsigned u[4]; short8 s; } r;
                r.u[0] = pk2(ra.x, ra.y); r.u[1] = pk2(ra.z, ra.w);
                r.u[2] = pk2(rb.x, rb.y); r.u[3] = pk2(rb.z, rb.w);
                acc[m][0] = __builtin_amdgcn_mfma_f32_16x16x32_bf16(bfc[ks * 2 + 0], r.s, acc[m][0], 0, 0, 0);
                acc[m][1] = __builtin_amdgcn_mfma_f32_16x16x32_bf16(bfc[ks * 2 + 1], r.s, acc[m][1], 0, 0, 0);
            }
        }
        __syncthreads();
        if (t + 1 < nt) {
            #pragma unroll
            for (int i = 0; i < 4; ++i) bfc[i] = bfn[i];
        }
    }

    // epilogue: lane owns row (m*16+lrow), cols w*32 + n*16 + lgrp*4 + j
    float sc[2][4], sh[2][4];
    #pragma unroll
    for (int n = 0; n < 2; ++n)
        #pragma unroll
        for (int j = 0; j < 4; ++j) {
            int gc = w * 32 + n * 16 + lgrp * 4 + j;
            float s = gamma[gc] * rsqrtf(var[gc] + 1e-5f);
            sc[n][j] = s;
            sh[n][j] = (bias[gc] - mean[gc]) * s + beta[gc];
        }
    #pragma unroll
    for (int m = 0; m < 4; ++m) {
        int row = m0 + m * 16 + lrow;
        if (row < M) {
            #pragma unroll
            for (int n = 0; n < 2; ++n) {
                float v0 = fmaxf(acc[m][n][0] * sc[n][0] + sh[n][0], 0.f);
                float v1 = fmaxf(acc[m][n][1] * sc[n][1] + sh[n][1], 0.f);
                float v2 = fmaxf(acc[m][n][2] * sc[n][2] + sh[n][2], 0.f);
                float v3 = fmaxf(acc[m][n][3] * sc[n][3] + sh[n][3], 0.f);
                *reinterpret_cast<uint2*>(out + (size_t)row * HID + w * 32 + n * 16 + lgrp * 4) =
                    make_uint2(pk2(v0, v1), pk2(v2, v3));
            }
        }
    }
}

// ---------------------------------------------------------------------------
// FUSED SAGE dual GEMM (both sides): out = [relu](Aagg @ WA^T + bl + Bx @ WB^T)
// All operands bf16; async-staged double-buffered LDS; bf16 output.
// ---------------------------------------------------------------------------
__global__ __launch_bounds__(256) void sage_mfma(
    const unsigned short* __restrict__ AaggJ, const unsigned short* __restrict__ BxJ,
    const unsigned short* __restrict__ WAj, const unsigned short* __restrict__ WBj,
    const float* __restrict__ blJ, unsigned short* __restrict__ outJ,
    const unsigned short* __restrict__ AaggU, const unsigned short* __restrict__ BxU,
    const unsigned short* __restrict__ WAu, const unsigned short* __restrict__ WBu,
    const float* __restrict__ blU, unsigned short* __restrict__ outU,
    int doRelu) {
    __shared__ unsigned short lds[2][4096];   // 2 x 8KB: [64 rows][64 bf16]
    const unsigned short *Aagg, *Bx, *WA, *WB; const float* bl; unsigned short* out;
    int M, m0;
    if (blockIdx.x < TBJ) {
        Aagg = AaggJ; Bx = BxJ; WA = WAj; WB = WBj; bl = blJ; out = outJ;
        M = N_JOBS; m0 = blockIdx.x * 64;
    } else {
        Aagg = AaggU; Bx = BxU; WA = WAu; WB = WBu; bl = blU; out = outU;
        M = N_USERS; m0 = (blockIdx.x - TBJ) * 64;
    }
    int tid = threadIdx.x;
    int w = tid >> 6, lane = tid & 63;
    int lrow = lane & 15, lgrp = lane >> 4;
    f32x4 acc[4][2];
    #pragma unroll
    for (int m = 0; m < 4; ++m)
        #pragma unroll
        for (int n = 0; n < 2; ++n) acc[m][n] = (f32x4){0.f, 0.f, 0.f, 0.f};

    auto STAGE = [&](int s, int b) {          // 2 x gl_lds16 per thread
        const unsigned short* Ap = (s < 2) ? Aagg : Bx;
        int k0 = (s & 1) << 6;
        #pragma unroll
        for (int c = 0; c < 2; ++c) {
            int unit = c * 256 + tid;         // 16B unit (512 total)
            int row = unit >> 3, u = unit & 7;
            int gr = m0 + row; if (gr > M - 1) gr = M - 1;
            const unsigned short* g = Ap + (size_t)gr * HID + k0 + ((u ^ (row & 7)) << 3);
            gl_lds16(g, (void*)&lds[b][unit * 8]);
        }
    };
    auto LOADW = [&](int s, short8* dst) {
        const unsigned short* Wp = (s < 2) ? WA : WB;
        int k0 = (s & 1) << 6;
        #pragma unroll
        for (int ks = 0; ks < 2; ++ks)
            #pragma unroll
            for (int n = 0; n < 2; ++n)
                dst[ks * 2 + n] = *reinterpret_cast<const short8*>(
                    Wp + (size_t)(w * 32 + n * 16 + lrow) * HID + k0 + ks * 32 + lgrp * 8);
    };

    short8 bfc[4], bfn[4];
    LOADW(0, bfc);
    STAGE(0, 0);
    __syncthreads();
    #pragma unroll
    for (int s = 0; s < 4; ++s) {
        if (s < 3) { LOADW(s + 1, bfn); STAGE(s + 1, (s + 1) & 1); }
        const unsigned short* bufp = &lds[s & 1][0];
        #pragma unroll
        for (int ks = 0; ks < 2; ++ks) {
            int p = ks * 4 + lgrp;
            #pragma unroll
            for (int m = 0; m < 4; ++m) {
                int row = m * 16 + lrow;
                short8 af = *reinterpret_cast<const short8*>(bufp + row * 64 + ((p ^ (row & 7)) << 3));
                acc[m][0] = __builtin_amdgcn_mfma_f32_16x16x32_bf16(bfc[ks * 2 + 0], af, acc[m][0], 0, 0, 0);
                acc[m][1] = __builtin_amdgcn_mfma_f32_16x16x32_bf16(bfc[ks * 2 + 1], af, acc[m][1], 0, 0, 0);
            }
        }
        __syncthreads();
        if (s < 3) {
            #pragma unroll
            for (int i = 0; i < 4; ++i) bfc[i] = bfn[i];
        }
    }

    // epilogue: lane owns row (m*16+lrow), cols w*32 + n*16 + lgrp*4 + j
    float blv[2][4];
    #pragma unroll
    for (int n = 0; n < 2; ++n)
        #pragma unroll
        for (int j = 0; j < 4; ++j)
            blv[n][j] = bl[w * 32 + n * 16 + lgrp * 4 + j];
    #pragma unroll
    for (int m = 0; m < 4; ++m) {
        int row = m0 + m * 16 + lrow;
        if (row < M) {
            #pragma unroll
            for (int n = 0; n < 2; ++n) {
                float v[4];
                #pragma unroll
                for (int j = 0; j < 4; ++j) {
                    float x = acc[m][n][j] + blv[n][j];
                    v[j] = doRelu ? fmaxf(x, 0.f) : x;
                }
                *reinterpret_cast<uint2*>(out + (size_t)row * HID + w * 32 + n * 16 + lgrp * 4) =
                    make_uint2(pk2(v[0], v[1]), pk2(v[2], v[3]));
            }
        }
    }
}

// ---------------------------------------------------------------------------
// Link readout: 32 lanes per label edge (2 edges/wave), bf16 inputs (8B/lane),
// fp32 accumulation.
// ---------------------------------------------------------------------------
__global__ __launch_bounds__(256) void dot_kernel(const unsigned short* __restrict__ U,
                                                  const unsigned short* __restrict__ J,
                                                  const int* __restrict__ ls,
                                                  const int* __restrict__ ld,
                                                  float* __restrict__ out, int nL) {
    int ew = (int)((blockIdx.x * blockDim.x + threadIdx.x) >> 5);
    int hl = threadIdx.x & 31;
    if (ew >= nL) return;
    int a = ls[ew], c = ld[ew];
    uint2 uv = *reinterpret_cast<const uint2*>(U + (size_t)a * HID + hl * 4);
    uint2 jv = *reinterpret_cast<const uint2*>(J + (size_t)c * HID + hl * 4);
    float p = b2f(uv.x & 0xffffu) * b2f(jv.x & 0xffffu)
            + b2f(uv.x >> 16)     * b2f(jv.x >> 16)
            + b2f(uv.y & 0xffffu) * b2f(jv.y & 0xffffu)
            + b2f(uv.y >> 16)     * b2f(jv.y >> 16);
    #pragma unroll
    for (int s = 16; s > 0; s >>= 1) p += __shfl_xor(p, s, 64);
    if (hl == 0) out[ew] = p;
}

// ---------------------------------------------------------------------------
extern "C" void kernel_launch(void* const* d_in, const int* in_sizes, int n_in,
                              void* d_out, int out_size, void* d_ws, size_t ws_size,
                              hipStream_t stream) {
    const float* user_x     = (const float*)d_in[0];
    const float* job_x      = (const float*)d_in[1];
    const float* user_W     = (const float*)d_in[2];
    const float* user_b     = (const float*)d_in[3];
    const float* user_gamma = (const float*)d_in[4];
    const float* user_beta  = (const float*)d_in[5];
    const float* user_mean  = (const float*)d_in[6];
    const float* user_var   = (const float*)d_in[7];
    const float* job_W      = (const float*)d_in[8];
    const float* job_b      = (const float*)d_in[9];
    const float* job_gamma  = (const float*)d_in[10];
    const float* job_beta   = (const float*)d_in[11];
    const float* job_mean   = (const float*)d_in[12];
    const float* job_var    = (const float*)d_in[13];
    const float* l1_rates_Wl = (const float*)d_in[14];
    const float* l1_rates_Wr = (const float*)d_in[15];
    const float* l1_rev_Wl   = (const float*)d_in[16];
    const float* l1_rev_Wr   = (const float*)d_in[17];
    const float* l2_rates_Wl = (const float*)d_in[18];
    const float* l2_rates_Wr = (const float*)d_in[19];
    const float* l2_rev_Wl   = (const float*)d_in[20];
    const float* l2_rev_Wr   = (const float*)d_in[21];
    const float* l1_rates_bl = (const float*)d_in[22];
    const float* l1_rev_bl   = (const float*)d_in[23];
    const float* l2_rates_bl = (const float*)d_in[24];
    const float* l2_rev_bl   = (const float*)d_in[25];
    const int* rates_src = (const int*)d_in[26];
    const int* rates_dst = (const int*)d_in[27];
    const int* label_src = (const int*)d_in[28];
    const int* label_dst = (const int*)d_in[29];

    // ---- workspace layout ----
    char* ws = (char*)d_ws;
    size_t o = 0;
    auto alloc = [&](size_t bytes) -> void* {
        void* p = ws + o;
        o = (o + bytes + 511) & ~(size_t)511;
        return p;
    };
    unsigned short* u_bf = (unsigned short*)alloc((size_t)N_USERS * HID * 2);
    unsigned short* j_bf = (unsigned short*)alloc((size_t)N_JOBS  * HID * 2);
    unsigned short* u1   = (unsigned short*)alloc((size_t)N_USERS * HID * 2);
    unsigned short* j1   = (unsigned short*)alloc((size_t)N_JOBS  * HID * 2);
    unsigned short* aggU = (unsigned short*)alloc((size_t)N_USERS * HID * 2);
    unsigned short* aggJ = (unsigned short*)alloc((size_t)N_JOBS  * HID * 2);
    unsigned short* u2b  = (unsigned short*)alloc((size_t)N_USERS * HID * 2);
    unsigned short* j2b  = (unsigned short*)alloc((size_t)N_JOBS  * HID * 2);
    int* vals_j = (int*)alloc((size_t)N_EDGES * 4);
    int* vals_u = (int*)alloc((size_t)N_EDGES * 4);
    unsigned* stage_j = (unsigned*)alloc((size_t)N_EDGES * 4);
    unsigned* stage_u = (unsigned*)alloc((size_t)N_EDGES * 4);
    int* off_j  = (int*)alloc((size_t)(N_JOBS + 1) * 4);
    int* off_u  = (int*)alloc((size_t)(N_USERS + 1) * 4);
    int* bcnt_j = (int*)alloc((size_t)(NBJ + 1) * 4);
    int* bcnt_u = (int*)alloc((size_t)(NBU + 1) * 4);
    int* boff_j = (int*)alloc((size_t)(NBJ + 1) * 4);
    int* boff_u = (int*)alloc((size_t)(NBU + 1) * 4);
    int* bcur_j = (int*)alloc((size_t)(NBJ + 1) * 4);
    int* bcur_u = (int*)alloc((size_t)(NBU + 1) * 4);
    unsigned short* wbf = (unsigned short*)alloc((size_t)294912 * 2);
    (void)ws_size; (void)n_in; (void)in_sizes; (void)out_size;

    const unsigned short* uWb = wbf;
    const unsigned short* jWb = wbf + 65536;
    const unsigned short* w8  = wbf + 163840;   // 8 x [128][128]

    // ---- weight conversion + bcnt zeroing (once per call, tiny) ----
    cvt_weights<<<289, 256, 0, stream>>>(user_W, job_W,
        l1_rates_Wl, l1_rates_Wr, l1_rev_Wl, l1_rev_Wr,
        l2_rates_Wl, l2_rates_Wr, l2_rev_Wl, l2_rev_Wr, wbf, bcnt_j, bcnt_u);

    // ---- CSR build (binned, shared by both layers) ----
    bucket_hist<<<512, 256, 0, stream>>>(rates_src, rates_dst, N_EDGES, bcnt_j, bcnt_u);
    bucket_scan<<<2, 1024, 0, stream>>>(bcnt_j, boff_j, bcur_j, bcnt_u, boff_u, bcur_u);
    csr_pass1<<<(N_EDGES + P1CHUNK - 1) / P1CHUNK, 256, 0, stream>>>(
        rates_src, rates_dst, N_EDGES, bcur_j, bcur_u, stage_j, stage_u);
    csr_pass2<<<NBJ + NBU, 256, 0, stream>>>(stage_j, boff_j, off_j, vals_j,
                                             stage_u, boff_u, off_u, vals_u);

    // ---- fused encoders ----
    encoder_mfma<<<TBU + TBJ, 256, 0, stream>>>(
        user_x, uWb, user_b, user_gamma, user_beta, user_mean, user_var,
        job_x, jWb, job_b, job_gamma, job_beta, job_mean, job_var,
        u_bf, j_bf);

    // ---- SAGE layer 1 (fused aggregation, fused GEMM, relu) ----
    aggregate2<<<ABJ + ABU, 256, 0, stream>>>(u_bf, off_j, vals_j, aggJ,
                                              j_bf, off_u, vals_u, aggU);
    sage_mfma<<<TBJ + TBU, 256, 0, stream>>>(
        aggJ, j_bf, w8 + 0 * 16384, w8 + 1 * 16384, l1_rates_bl, j1,
        aggU, u_bf, w8 + 2 * 16384, w8 + 3 * 16384, l1_rev_bl,   u1, 1);

    // ---- SAGE layer 2 (fused, no relu, bf16 out) ----
    aggregate2<<<ABJ + ABU, 256, 0, stream>>>(u1, off_j, vals_j, aggJ,
                                              j1, off_u, vals_u, aggU);
    sage_mfma<<<TBJ + TBU, 256, 0, stream>>>(
        aggJ, j1, w8 + 4 * 16384, w8 + 5 * 16384, l2_rates_bl, j2b,
        aggU, u1, w8 + 6 * 16384, w8 + 7 * 16384, l2_rev_bl,   u2b, 0);

    // ---- link readout (bf16 gathers, fp32 accum) ----
    dot_kernel<<<(N_LABELS * 32 + 255) / 256, 256, 0, stream>>>(
        u2b, j2b, label_src, label_dst, (float*)d_out, N_LABELS);
}

// Round 14
// 574.375 us; speedup vs baseline: 1.2628x; 1.0217x over previous
//
#include <hip/hip_runtime.h>
#include <cstdint>
#include <cstddef>

#define HID 128
#define N_USERS 100000
#define N_JOBS  50000
#define N_EDGES 2000000
#define N_LABELS 500000

#define RBITS 8
#define RSIZE 256
#define NBJ ((N_JOBS  + RSIZE - 1) / RSIZE)   // 196
#define NBU ((N_USERS + RSIZE - 1) / RSIZE)   // 391
#define P1CHUNK 8192

// GEMM tiling (64-row tiles)
#define TBU ((N_USERS + 63) / 64)   // 1563
#define TBJ ((N_JOBS  + 63) / 64)   // 782
// aggregation blocks (4 nodes per 256-thread block)
#define ABJ ((N_JOBS  + 3) / 4)     // 12500
#define ABU ((N_USERS + 3) / 4)     // 25000

typedef __attribute__((ext_vector_type(8))) short short8;
typedef __attribute__((ext_vector_type(4))) float f32x4;

__device__ __forceinline__ unsigned short f2b(float f) {
    union { float f; unsigned u; } v; v.f = f;
    unsigned r = v.u + 0x7FFFu + ((v.u >> 16) & 1u);   // RNE to bf16
    return (unsigned short)(r >> 16);
}
__device__ __forceinline__ float b2f(unsigned h) {
    union { unsigned u; float f; } v; v.u = h << 16;
    return v.f;
}
__device__ __forceinline__ unsigned pk2(float lo, float hi) {
    return (unsigned)f2b(lo) | ((unsigned)f2b(hi) << 16);
}
// async global->LDS, 16B per lane; LDS dest = wave-uniform base + lane*16
__device__ __forceinline__ void gl_lds16(const void* g, void* l) {
    __builtin_amdgcn_global_load_lds(
        (const __attribute__((address_space(1))) unsigned int*)g,
        (__attribute__((address_space(3))) unsigned int*)l, 16, 0, 0);
}

// ---------------------------------------------------------------------------
// One-shot: convert all 10 weight matrices fp32 -> bf16 into ws.
// Block 288 also zeroes the bucket-count arrays (replaces 2 memsets).
// ---------------------------------------------------------------------------
__global__ __launch_bounds__(256) void cvt_weights(
    const float* __restrict__ uW, const float* __restrict__ jW,
    const float* __restrict__ a, const float* __restrict__ b,
    const float* __restrict__ c, const float* __restrict__ d,
    const float* __restrict__ e, const float* __restrict__ f,
    const float* __restrict__ g, const float* __restrict__ h,
    unsigned short* __restrict__ ow,
    int* __restrict__ bcnt_j, int* __restrict__ bcnt_u) {
    if (blockIdx.x == 288) {   // dedicated zeroing block
        for (int i = threadIdx.x; i <= NBJ; i += 256) bcnt_j[i] = 0;
        for (int i = threadIdx.x; i <= NBU; i += 256) bcnt_u[i] = 0;
        return;
    }
    int i4 = blockIdx.x * 256 + threadIdx.x;   // float4 index
    if (i4 >= 73728) return;                    // 294912 floats total
    int i = i4 * 4;
    const float* src; int base;
    if (i < 65536)       { src = uW; base = 0; }
    else if (i < 163840) { src = jW; base = 65536; }
    else {
        int k = (i - 163840) >> 14;
        const float* s4 = (k < 4) ? ((k < 2) ? (k == 0 ? a : b) : (k == 2 ? c : d))
                                  : ((k < 6) ? (k == 4 ? e : f) : (k == 6 ? g : h));
        src = s4; base = 163840 + (k << 14);
    }
    float4 v = *reinterpret_cast<const float4*>(src + (i - base));
    *reinterpret_cast<uint2*>(ow + i) = make_uint2(pk2(v.x, v.y), pk2(v.z, v.w));
}

// ---------------------------------------------------------------------------
// CSR build stage 1: bucket histogram (both sides), LDS-aggregated
// ---------------------------------------------------------------------------
__global__ __launch_bounds__(256) void bucket_hist(const int* __restrict__ src,
                                                   const int* __restrict__ dst,
                                                   int nE, int* __restrict__ bcnt_j,
                                                   int* __restrict__ bcnt_u) {
    __shared__ int hj[NBJ];
    __shared__ int hu[NBU];
    int t = threadIdx.x;
    for (int i = t; i < NBJ; i += 256) hj[i] = 0;
    for (int i = t; i < NBU; i += 256) hu[i] = 0;
    __syncthreads();
    int i = blockIdx.x * blockDim.x + t;
    int stride = gridDim.x * blockDim.x;
    for (; i < nE; i += stride) {
        atomicAdd(&hj[dst[i] >> RBITS], 1);
        atomicAdd(&hu[src[i] >> RBITS], 1);
    }
    __syncthreads();
    for (int i2 = t; i2 < NBJ; i2 += 256) if (hj[i2]) atomicAdd(&bcnt_j[i2], hj[i2]);
    for (int i2 = t; i2 < NBU; i2 += 256) if (hu[i2]) atomicAdd(&bcnt_u[i2], hu[i2]);
}

// ---------------------------------------------------------------------------
// CSR build stage 2: exclusive scan of bucket counts (one block per side)
// ---------------------------------------------------------------------------
__global__ __launch_bounds__(1024) void bucket_scan(int* __restrict__ bcnt_j, int* __restrict__ boff_j,
                                                    int* __restrict__ bcur_j,
                                                    int* __restrict__ bcnt_u, int* __restrict__ boff_u,
                                                    int* __restrict__ bcur_u) {
    int* bcnt = blockIdx.x ? bcnt_u : bcnt_j;
    int* boff = blockIdx.x ? boff_u : boff_j;
    int* bcur = blockIdx.x ? bcur_u : bcur_j;
    int n = blockIdx.x ? NBU : NBJ;
    __shared__ int sm[1024];
    int t = threadIdx.x;
    int v = (t < n) ? bcnt[t] : 0;
    sm[t] = v;
    __syncthreads();
    for (int d = 1; d < 1024; d <<= 1) {
        int q = (t >= d) ? sm[t - d] : 0;
        __syncthreads();
        sm[t] += q;
        __syncthreads();
    }
    if (t < n) { int e = sm[t] - v; boff[t] = e; bcur[t] = e; }
    if (t == 0) boff[n] = N_EDGES;
}

// ---------------------------------------------------------------------------
// CSR build stage 3: LDS-binned radix partition (bulk-reserved runs)
// ---------------------------------------------------------------------------
__global__ __launch_bounds__(256) void csr_pass1(const int* __restrict__ src,
                                                 const int* __restrict__ dst,
                                                 int nE, int* __restrict__ gcur_j,
                                                 int* __restrict__ gcur_u,
                                                 unsigned* __restrict__ stage_j,
                                                 unsigned* __restrict__ stage_u) {
    __shared__ int cur_j[NBJ];
    __shared__ int cur_u[NBU];
    int t = threadIdx.x;
    int e0 = blockIdx.x * P1CHUNK;
    int e1 = min(e0 + P1CHUNK, nE);
    for (int i = t; i < NBJ; i += 256) cur_j[i] = 0;
    for (int i = t; i < NBU; i += 256) cur_u[i] = 0;
    __syncthreads();
    for (int e = e0 + t; e < e1; e += 256) {
        atomicAdd(&cur_j[dst[e] >> RBITS], 1);
        atomicAdd(&cur_u[src[e] >> RBITS], 1);
    }
    __syncthreads();
    for (int i = t; i < NBJ; i += 256) {
        int c = cur_j[i];
        cur_j[i] = c ? atomicAdd(&gcur_j[i], c) : 0;
    }
    for (int i = t; i < NBU; i += 256) {
        int c = cur_u[i];
        cur_u[i] = c ? atomicAdd(&gcur_u[i], c) : 0;
    }
    __syncthreads();
    for (int e = e0 + t; e < e1; e += 256) {
        int d = dst[e], s = src[e];
        int pj = atomicAdd(&cur_j[d >> RBITS], 1);
        stage_j[pj] = ((unsigned)(d & (RSIZE - 1)) << 24) | (unsigned)s;
        int pu = atomicAdd(&cur_u[s >> RBITS], 1);
        stage_u[pu] = ((unsigned)(s & (RSIZE - 1)) << 24) | (unsigned)d;
    }
}

// ---------------------------------------------------------------------------
// CSR build stage 4: per-bucket reorder (256 nodes/bucket)
// ---------------------------------------------------------------------------
__global__ __launch_bounds__(256) void csr_pass2(
    const unsigned* __restrict__ stage_j, const int* __restrict__ boff_j,
    int* __restrict__ off_j, int* __restrict__ vals_j,
    const unsigned* __restrict__ stage_u, const int* __restrict__ boff_u,
    int* __restrict__ off_u, int* __restrict__ vals_u) {
    __shared__ int cnt[RSIZE];
    __shared__ int sc[RSIZE];
    __shared__ int cur[RSIZE];
    int borig = blockIdx.x, t = threadIdx.x;
    const unsigned* words; const int* boff; int* off; int* vals; int b; int nNodes;
    if (borig < NBJ) { words = stage_j; boff = boff_j; off = off_j; vals = vals_j; b = borig; nNodes = N_JOBS; }
    else             { words = stage_u; boff = boff_u; off = off_u; vals = vals_u; b = borig - NBJ; nNodes = N_USERS; }
    int node0 = b << RBITS;
    int sbeg = boff[b], send = boff[b + 1];
    cnt[t] = 0;
    __syncthreads();
    for (int e = sbeg + t; e < send; e += 256) {
        atomicAdd(&cnt[words[e] >> 24], 1);
    }
    __syncthreads();
    int v = cnt[t];
    sc[t] = v;
    __syncthreads();
    #pragma unroll
    for (int d = 1; d < RSIZE; d <<= 1) {
        int q = (t >= d) ? sc[t - d] : 0;
        __syncthreads();
        sc[t] += q;
        __syncthreads();
    }
    int node = node0 + t;
    if (node < nNodes) {
        int base = sbeg + sc[t] - v;   // exclusive
        off[node] = base;
        cur[t] = base;
    }
    __syncthreads();
    for (int e = sbeg + t; e < send; e += 256) {
        unsigned w = words[e];
        int slot = atomicAdd(&cur[w >> 24], 1);
        vals[slot] = (int)(w & 0xFFFFFFu);
    }
    if (t == 0 && borig == 0)   off_j[N_JOBS]  = N_EDGES;
    if (t == 0 && borig == NBJ) off_u[N_USERS] = N_EDGES;
}

// ---------------------------------------------------------------------------
// FUSED mean aggregation (both sides in one launch). One wave per node;
// the two 32-lane halves process edges e and e+1 concurrently (8B loads);
// 4-pair unroll -> 8 edges in flight; combined via shfl_xor(32) at the end.
// ---------------------------------------------------------------------------
__global__ __launch_bounds__(256) void aggregate2(
    const unsigned short* __restrict__ xJ, const int* __restrict__ offJ,
    const int* __restrict__ valsJ, unsigned short* __restrict__ outJ,
    const unsigned short* __restrict__ xU, const int* __restrict__ offU,
    const int* __restrict__ valsU, unsigned short* __restrict__ outU) {
    int bb = blockIdx.x;
    const unsigned short* x; const int* off; const int* vals; unsigned short* out;
    int nDst, node0;
    if (bb < ABJ) { x = xJ; off = offJ; vals = valsJ; out = outJ; nDst = N_JOBS;  node0 = bb * 4; }
    else          { x = xU; off = offU; vals = valsU; out = outU; nDst = N_USERS; node0 = (bb - ABJ) * 4; }
    int node = node0 + (threadIdx.x >> 6);
    if (node >= nDst) return;
    int lane = threadIdx.x & 63;
    int hl = lane & 31;           // half-lane: feature group (8B)
    int eo = lane >> 5;           // which edge of the pair
    const unsigned short* xb = x + hl * 4;
    int beg = off[node], end = off[node + 1];
    float a0 = 0.f, a1 = 0.f, a2 = 0.f, a3 = 0.f;
    int e = beg;
    for (; e + 7 < end; e += 8) {
        int s0 = vals[e + eo],     s1 = vals[e + 2 + eo];
        int s2 = vals[e + 4 + eo], s3 = vals[e + 6 + eo];
        uint2 v0 = *reinterpret_cast<const uint2*>(xb + (size_t)s0 * HID);
        uint2 v1 = *reinterpret_cast<const uint2*>(xb + (size_t)s1 * HID);
        uint2 v2 = *reinterpret_cast<const uint2*>(xb + (size_t)s2 * HID);
        uint2 v3 = *reinterpret_cast<const uint2*>(xb + (size_t)s3 * HID);
        a0 += b2f(v0.x & 0xffffu) + b2f(v1.x & 0xffffu) + b2f(v2.x & 0xffffu) + b2f(v3.x & 0xffffu);
        a1 += b2f(v0.x >> 16)     + b2f(v1.x >> 16)     + b2f(v2.x >> 16)     + b2f(v3.x >> 16);
        a2 += b2f(v0.y & 0xffffu) + b2f(v1.y & 0xffffu) + b2f(v2.y & 0xffffu) + b2f(v3.y & 0xffffu);
        a3 += b2f(v0.y >> 16)     + b2f(v1.y >> 16)     + b2f(v2.y >> 16)     + b2f(v3.y >> 16);
    }
    for (; e < end; e += 2) {
        int ee = e + eo;
        if (ee < end) {
            int s = vals[ee];
            uint2 v = *reinterpret_cast<const uint2*>(xb + (size_t)s * HID);
            a0 += b2f(v.x & 0xffffu);
            a1 += b2f(v.x >> 16);
            a2 += b2f(v.y & 0xffffu);
            a3 += b2f(v.y >> 16);
        }
    }
    a0 += __shfl_xor(a0, 32, 64);
    a1 += __shfl_xor(a1, 32, 64);
    a2 += __shfl_xor(a2, 32, 64);
    a3 += __shfl_xor(a3, 32, 64);
    if (eo == 0) {
        float inv = 1.0f / fmaxf((float)(end - beg), 1.0f);
        *reinterpret_cast<uint2*>(out + (size_t)node * HID + hl * 4) =
            make_uint2(pk2(a0 * inv, a1 * inv), pk2(a2 * inv, a3 * inv));
    }
}

// ---------------------------------------------------------------------------
// FUSED encoder (user + job sides): out_bf16 = relu(BN(X @ W^T + b)).
// 64x128 tile, BK=64. X staged fp32 via async global_load_lds (dbuf, XOR
// swizzle), then converted ONCE per tile into a swizzled bf16 LDS buffer by
// a block-wide CONVERT phase (4096 conversions/block instead of 16384).
// MFMA phase is pure ds_read_b128 + MFMA (zero conversion VALU).
// ---------------------------------------------------------------------------
__global__ __launch_bounds__(256) void encoder_mfma(
    const float* __restrict__ Xu, const unsigned short* __restrict__ Wbu,
    const float* __restrict__ bu, const float* __restrict__ gu,
    const float* __restrict__ beu, const float* __restrict__ mu,
    const float* __restrict__ vu,
    const float* __restrict__ Xj, const unsigned short* __restrict__ Wbj,
    const float* __restrict__ bj, const float* __restrict__ gj,
    const float* __restrict__ bej, const float* __restrict__ mj,
    const float* __restrict__ vj,
    unsigned short* __restrict__ outU, unsigned short* __restrict__ outJ) {
    __shared__ float l32[2][4096];            // 32 KB fp32 staging (dbuf)
    __shared__ unsigned short lb16[4096];     // 8 KB bf16 tile (single)
    const float *X, *bias, *gamma, *beta, *mean, *var;
    const unsigned short* Wb; unsigned short* out;
    int M, K, m0;
    if (blockIdx.x < TBU) {
        X = Xu; Wb = Wbu; bias = bu; gamma = gu; beta = beu; mean = mu; var = vu;
        out = outU; M = N_USERS; K = 512; m0 = blockIdx.x * 64;
    } else {
        X = Xj; Wb = Wbj; bias = bj; gamma = gj; beta = bej; mean = mj; var = vj;
        out = outJ; M = N_JOBS; K = 768; m0 = (blockIdx.x - TBU) * 64;
    }
    int tid = threadIdx.x;
    int w = tid >> 6, lane = tid & 63;
    int lrow = lane & 15, lgrp = lane >> 4;
    f32x4 acc[4][2];
    #pragma unroll
    for (int m = 0; m < 4; ++m)
        #pragma unroll
        for (int n = 0; n < 2; ++n) acc[m][n] = (f32x4){0.f, 0.f, 0.f, 0.f};

    const unsigned short* wp[2];
    #pragma unroll
    for (int n = 0; n < 2; ++n)
        wp[n] = Wb + (size_t)(w * 32 + n * 16 + lrow) * K + lgrp * 8;

    auto STAGE = [&](int t, int b) {          // 4 x gl_lds16 per thread
        int k0 = t << 6;
        #pragma unroll
        for (int c = 0; c < 4; ++c) {
            int unit = c * 256 + tid;         // fp32 16B unit (1024 total)
            int row = unit >> 4, u = unit & 15;
            int gr = m0 + row; if (gr > M - 1) gr = M - 1;
            const float* g = X + (size_t)gr * K + k0 + ((u ^ (row & 15)) << 2);
            gl_lds16(g, (void*)&l32[b][unit * 4]);
        }
    };
    auto CONVERT = [&](int b) {               // fp32 tile -> swizzled bf16 tile
        const float* src = &l32[b][0];
        #pragma unroll
        for (int c = 0; c < 2; ++c) {
            int q = c * 256 + tid;            // bf16 16B unit (512 total)
            int row = q >> 3, u = q & 7;
            int swz = row & 15;
            float4 a = *reinterpret_cast<const float4*>(src + row * 64 + (((2 * u)     ^ swz) << 2));
            float4 bv = *reinterpret_cast<const float4*>(src + row * 64 + (((2 * u + 1) ^ swz) << 2));
            uint4 r = make_uint4(pk2(a.x, a.y), pk2(a.z, a.w), pk2(bv.x, bv.y), pk2(bv.z, bv.w));
            *reinterpret_cast<uint4*>(lb16 + row * 64 + ((u ^ (row & 7)) << 3)) = r;
        }
    };
    auto LOADW = [&](int t, short8* dst) {    // dst[ks*2+n], W frags for step t
        int k0 = t << 6;
        #pragma unroll
        for (int ks = 0; ks < 2; ++ks)
            #pragma unroll
            for (int n = 0; n < 2; ++n)
                dst[ks * 2 + n] = *reinterpret_cast<const short8*>(wp[n] + k0 + ks * 32);
    };

    int nt = K >> 6;
    short8 bfc[4], bfn[4];
    LOADW(0, bfc);
    STAGE(0, 0);
    __syncthreads();                          // drain DMA for step 0
    CONVERT(0);
    __syncthreads();                          // lb16 ready
    for (int t = 0; t < nt; ++t) {
        if (t + 1 < nt) { LOADW(t + 1, bfn); STAGE(t + 1, (t + 1) & 1); }
        #pragma unroll
        for (int ks = 0; ks < 2; ++ks) {
            int p = ks * 4 + lgrp;
            #pragma unroll
            for (int m = 0; m < 4; ++m) {
                int row = m * 16 + lrow;
                short8 af = *reinterpret_cast<const short8*>(lb16 + row * 64 + ((p ^ (row & 7)) << 3));
                acc[m][0] = __builtin_amdgcn_mfma_f32_16x16x32_bf16(bfc[ks * 2 + 0], af, acc[m][0], 0, 0, 0);
                acc[m][1] = __builtin_amdgcn_mfma_f32_16x16x32_bf16(bfc[ks * 2 + 1], af, acc[m][1], 0, 0, 0);
            }
        }
        __syncthreads();                      // lb16 reads done; t+1 DMA drained
        if (t + 1 < nt) {
            CONVERT((t + 1) & 1);             // FIX: buffer index, not step index
            __syncthreads();                  // lb16 ready for next step
            #pragma unroll
            for (int i = 0; i < 4; ++i) bfc[i] = bfn[i];
        }
    }

    // epilogue: lane owns row (m*16+lrow), cols w*32 + n*16 + lgrp*4 + j
    float sc[2][4], sh[2][4];
    #pragma unroll
    for (int n = 0; n < 2; ++n)
        #pragma unroll
        for (int j = 0; j < 4; ++j) {
            int gc = w * 32 + n * 16 + lgrp * 4 + j;
            float s = gamma[gc] * rsqrtf(var[gc] + 1e-5f);
            sc[n][j] = s;
            sh[n][j] = (bias[gc] - mean[gc]) * s + beta[gc];
        }
    #pragma unroll
    for (int m = 0; m < 4; ++m) {
        int row = m0 + m * 16 + lrow;
        if (row < M) {
            #pragma unroll
            for (int n = 0; n < 2; ++n) {
                float v0 = fmaxf(acc[m][n][0] * sc[n][0] + sh[n][0], 0.f);
                float v1 = fmaxf(acc[m][n][1] * sc[n][1] + sh[n][1], 0.f);
                float v2 = fmaxf(acc[m][n][2] * sc[n][2] + sh[n][2], 0.f);
                float v3 = fmaxf(acc[m][n][3] * sc[n][3] + sh[n][3], 0.f);
                *reinterpret_cast<uint2*>(out + (size_t)row * HID + w * 32 + n * 16 + lgrp * 4) =
                    make_uint2(pk2(v0, v1), pk2(v2, v3));
            }
        }
    }
}

// ---------------------------------------------------------------------------
// FUSED SAGE dual GEMM (both sides): out = [relu](Aagg @ WA^T + bl + Bx @ WB^T)
// All operands bf16; async-staged double-buffered LDS; bf16 output.
// ---------------------------------------------------------------------------
__global__ __launch_bounds__(256) void sage_mfma(
    const unsigned short* __restrict__ AaggJ, const unsigned short* __restrict__ BxJ,
    const unsigned short* __restrict__ WAj, const unsigned short* __restrict__ WBj,
    const float* __restrict__ blJ, unsigned short* __restrict__ outJ,
    const unsigned short* __restrict__ AaggU, const unsigned short* __restrict__ BxU,
    const unsigned short* __restrict__ WAu, const unsigned short* __restrict__ WBu,
    const float* __restrict__ blU, unsigned short* __restrict__ outU,
    int doRelu) {
    __shared__ unsigned short lds[2][4096];   // 2 x 8KB: [64 rows][64 bf16]
    const unsigned short *Aagg, *Bx, *WA, *WB; const float* bl; unsigned short* out;
    int M, m0;
    if (blockIdx.x < TBJ) {
        Aagg = AaggJ; Bx = BxJ; WA = WAj; WB = WBj; bl = blJ; out = outJ;
        M = N_JOBS; m0 = blockIdx.x * 64;
    } else {
        Aagg = AaggU; Bx = BxU; WA = WAu; WB = WBu; bl = blU; out = outU;
        M = N_USERS; m0 = (blockIdx.x - TBJ) * 64;
    }
    int tid = threadIdx.x;
    int w = tid >> 6, lane = tid & 63;
    int lrow = lane & 15, lgrp = lane >> 4;
    f32x4 acc[4][2];
    #pragma unroll
    for (int m = 0; m < 4; ++m)
        #pragma unroll
        for (int n = 0; n < 2; ++n) acc[m][n] = (f32x4){0.f, 0.f, 0.f, 0.f};

    auto STAGE = [&](int s, int b) {          // 2 x gl_lds16 per thread
        const unsigned short* Ap = (s < 2) ? Aagg : Bx;
        int k0 = (s & 1) << 6;
        #pragma unroll
        for (int c = 0; c < 2; ++c) {
            int unit = c * 256 + tid;         // 16B unit (512 total)
            int row = unit >> 3, u = unit & 7;
            int gr = m0 + row; if (gr > M - 1) gr = M - 1;
            const unsigned short* g = Ap + (size_t)gr * HID + k0 + ((u ^ (row & 7)) << 3);
            gl_lds16(g, (void*)&lds[b][unit * 8]);
        }
    };
    auto LOADW = [&](int s, short8* dst) {
        const unsigned short* Wp = (s < 2) ? WA : WB;
        int k0 = (s & 1) << 6;
        #pragma unroll
        for (int ks = 0; ks < 2; ++ks)
            #pragma unroll
            for (int n = 0; n < 2; ++n)
                dst[ks * 2 + n] = *reinterpret_cast<const short8*>(
                    Wp + (size_t)(w * 32 + n * 16 + lrow) * HID + k0 + ks * 32 + lgrp * 8);
    };

    short8 bfc[4], bfn[4];
    LOADW(0, bfc);
    STAGE(0, 0);
    __syncthreads();
    #pragma unroll
    for (int s = 0; s < 4; ++s) {
        if (s < 3) { LOADW(s + 1, bfn); STAGE(s + 1, (s + 1) & 1); }
        const unsigned short* bufp = &lds[s & 1][0];
        #pragma unroll
        for (int ks = 0; ks < 2; ++ks) {
            int p = ks * 4 + lgrp;
            #pragma unroll
            for (int m = 0; m < 4; ++m) {
                int row = m * 16 + lrow;
                short8 af = *reinterpret_cast<const short8*>(bufp + row * 64 + ((p ^ (row & 7)) << 3));
                acc[m][0] = __builtin_amdgcn_mfma_f32_16x16x32_bf16(bfc[ks * 2 + 0], af, acc[m][0], 0, 0, 0);
                acc[m][1] = __builtin_amdgcn_mfma_f32_16x16x32_bf16(bfc[ks * 2 + 1], af, acc[m][1], 0, 0, 0);
            }
        }
        __syncthreads();
        if (s < 3) {
            #pragma unroll
            for (int i = 0; i < 4; ++i) bfc[i] = bfn[i];
        }
    }

    // epilogue: lane owns row (m*16+lrow), cols w*32 + n*16 + lgrp*4 + j
    float blv[2][4];
    #pragma unroll
    for (int n = 0; n < 2; ++n)
        #pragma unroll
        for (int j = 0; j < 4; ++j)
            blv[n][j] = bl[w * 32 + n * 16 + lgrp * 4 + j];
    #pragma unroll
    for (int m = 0; m < 4; ++m) {
        int row = m0 + m * 16 + lrow;
        if (row < M) {
            #pragma unroll
            for (int n = 0; n < 2; ++n) {
                float v[4];
                #pragma unroll
                for (int j = 0; j < 4; ++j) {
                    float x = acc[m][n][j] + blv[n][j];
                    v[j] = doRelu ? fmaxf(x, 0.f) : x;
                }
                *reinterpret_cast<uint2*>(out + (size_t)row * HID + w * 32 + n * 16 + lgrp * 4) =
                    make_uint2(pk2(v[0], v[1]), pk2(v[2], v[3]));
            }
        }
    }
}

// ---------------------------------------------------------------------------
// Link readout: 32 lanes per label edge (2 edges/wave), bf16 inputs (8B/lane),
// fp32 accumulation.
// ---------------------------------------------------------------------------
__global__ __launch_bounds__(256) void dot_kernel(const unsigned short* __restrict__ U,
                                                  const unsigned short* __restrict__ J,
                                                  const int* __restrict__ ls,
                                                  const int* __restrict__ ld,
                                                  float* __restrict__ out, int nL) {
    int ew = (int)((blockIdx.x * blockDim.x + threadIdx.x) >> 5);
    int hl = threadIdx.x & 31;
    if (ew >= nL) return;
    int a = ls[ew], c = ld[ew];
    uint2 uv = *reinterpret_cast<const uint2*>(U + (size_t)a * HID + hl * 4);
    uint2 jv = *reinterpret_cast<const uint2*>(J + (size_t)c * HID + hl * 4);
    float p = b2f(uv.x & 0xffffu) * b2f(jv.x & 0xffffu)
            + b2f(uv.x >> 16)     * b2f(jv.x >> 16)
            + b2f(uv.y & 0xffffu) * b2f(jv.y & 0xffffu)
            + b2f(uv.y >> 16)     * b2f(jv.y >> 16);
    #pragma unroll
    for (int s = 16; s > 0; s >>= 1) p += __shfl_xor(p, s, 64);
    if (hl == 0) out[ew] = p;
}

// ---------------------------------------------------------------------------
extern "C" void kernel_launch(void* const* d_in, const int* in_sizes, int n_in,
                              void* d_out, int out_size, void* d_ws, size_t ws_size,
                              hipStream_t stream) {
    const float* user_x     = (const float*)d_in[0];
    const float* job_x      = (const float*)d_in[1];
    const float* user_W     = (const float*)d_in[2];
    const float* user_b     = (const float*)d_in[3];
    const float* user_gamma = (const float*)d_in[4];
    const float* user_beta  = (const float*)d_in[5];
    const float* user_mean  = (const float*)d_in[6];
    const float* user_var   = (const float*)d_in[7];
    const float* job_W      = (const float*)d_in[8];
    const float* job_b      = (const float*)d_in[9];
    const float* job_gamma  = (const float*)d_in[10];
    const float* job_beta   = (const float*)d_in[11];
    const float* job_mean   = (const float*)d_in[12];
    const float* job_var    = (const float*)d_in[13];
    const float* l1_rates_Wl = (const float*)d_in[14];
    const float* l1_rates_Wr = (const float*)d_in[15];
    const float* l1_rev_Wl   = (const float*)d_in[16];
    const float* l1_rev_Wr   = (const float*)d_in[17];
    const float* l2_rates_Wl = (const float*)d_in[18];
    const float* l2_rates_Wr = (const float*)d_in[19];
    const float* l2_rev_Wl   = (const float*)d_in[20];
    const float* l2_rev_Wr   = (const float*)d_in[21];
    const float* l1_rates_bl = (const float*)d_in[22];
    const float* l1_rev_bl   = (const float*)d_in[23];
    const float* l2_rates_bl = (const float*)d_in[24];
    const float* l2_rev_bl   = (const float*)d_in[25];
    const int* rates_src = (const int*)d_in[26];
    const int* rates_dst = (const int*)d_in[27];
    const int* label_src = (const int*)d_in[28];
    const int* label_dst = (const int*)d_in[29];

    // ---- workspace layout ----
    char* ws = (char*)d_ws;
    size_t o = 0;
    auto alloc = [&](size_t bytes) -> void* {
        void* p = ws + o;
        o = (o + bytes + 511) & ~(size_t)511;
        return p;
    };
    unsigned short* u_bf = (unsigned short*)alloc((size_t)N_USERS * HID * 2);
    unsigned short* j_bf = (unsigned short*)alloc((size_t)N_JOBS  * HID * 2);
    unsigned short* u1   = (unsigned short*)alloc((size_t)N_USERS * HID * 2);
    unsigned short* j1   = (unsigned short*)alloc((size_t)N_JOBS  * HID * 2);
    unsigned short* aggU = (unsigned short*)alloc((size_t)N_USERS * HID * 2);
    unsigned short* aggJ = (unsigned short*)alloc((size_t)N_JOBS  * HID * 2);
    unsigned short* u2b  = (unsigned short*)alloc((size_t)N_USERS * HID * 2);
    unsigned short* j2b  = (unsigned short*)alloc((size_t)N_JOBS  * HID * 2);
    int* vals_j = (int*)alloc((size_t)N_EDGES * 4);
    int* vals_u = (int*)alloc((size_t)N_EDGES * 4);
    unsigned* stage_j = (unsigned*)alloc((size_t)N_EDGES * 4);
    unsigned* stage_u = (unsigned*)alloc((size_t)N_EDGES * 4);
    int* off_j  = (int*)alloc((size_t)(N_JOBS + 1) * 4);
    int* off_u  = (int*)alloc((size_t)(N_USERS + 1) * 4);
    int* bcnt_j = (int*)alloc((size_t)(NBJ + 1) * 4);
    int* bcnt_u = (int*)alloc((size_t)(NBU + 1) * 4);
    int* boff_j = (int*)alloc((size_t)(NBJ + 1) * 4);
    int* boff_u = (int*)alloc((size_t)(NBU + 1) * 4);
    int* bcur_j = (int*)alloc((size_t)(NBJ + 1) * 4);
    int* bcur_u = (int*)alloc((size_t)(NBU + 1) * 4);
    unsigned short* wbf = (unsigned short*)alloc((size_t)294912 * 2);
    (void)ws_size; (void)n_in; (void)in_sizes; (void)out_size;

    const unsigned short* uWb = wbf;
    const unsigned short* jWb = wbf + 65536;
    const unsigned short* w8  = wbf + 163840;   // 8 x [128][128]

    // ---- weight conversion + bcnt zeroing (once per call, tiny) ----
    cvt_weights<<<289, 256, 0, stream>>>(user_W, job_W,
        l1_rates_Wl, l1_rates_Wr, l1_rev_Wl, l1_rev_Wr,
        l2_rates_Wl, l2_rates_Wr, l2_rev_Wl, l2_rev_Wr, wbf, bcnt_j, bcnt_u);

    // ---- CSR build (binned, shared by both layers) ----
    bucket_hist<<<512, 256, 0, stream>>>(rates_src, rates_dst, N_EDGES, bcnt_j, bcnt_u);
    bucket_scan<<<2, 1024, 0, stream>>>(bcnt_j, boff_j, bcur_j, bcnt_u, boff_u, bcur_u);
    csr_pass1<<<(N_EDGES + P1CHUNK - 1) / P1CHUNK, 256, 0, stream>>>(
        rates_src, rates_dst, N_EDGES, bcur_j, bcur_u, stage_j, stage_u);
    csr_pass2<<<NBJ + NBU, 256, 0, stream>>>(stage_j, boff_j, off_j, vals_j,
                                             stage_u, boff_u, off_u, vals_u);

    // ---- fused encoders ----
    encoder_mfma<<<TBU + TBJ, 256, 0, stream>>>(
        user_x, uWb, user_b, user_gamma, user_beta, user_mean, user_var,
        job_x, jWb, job_b, job_gamma, job_beta, job_mean, job_var,
        u_bf, j_bf);

    // ---- SAGE layer 1 (fused aggregation, fused GEMM, relu) ----
    aggregate2<<<ABJ + ABU, 256, 0, stream>>>(u_bf, off_j, vals_j, aggJ,
                                              j_bf, off_u, vals_u, aggU);
    sage_mfma<<<TBJ + TBU, 256, 0, stream>>>(
        aggJ, j_bf, w8 + 0 * 16384, w8 + 1 * 16384, l1_rates_bl, j1,
        aggU, u_bf, w8 + 2 * 16384, w8 + 3 * 16384, l1_rev_bl,   u1, 1);

    // ---- SAGE layer 2 (fused, no relu, bf16 out) ----
    aggregate2<<<ABJ + ABU, 256, 0, stream>>>(u1, off_j, vals_j, aggJ,
                                              j1, off_u, vals_u, aggU);
    sage_mfma<<<TBJ + TBU, 256, 0, stream>>>(
        aggJ, j1, w8 + 4 * 16384, w8 + 5 * 16384, l2_rates_bl, j2b,
        aggU, u1, w8 + 6 * 16384, w8 + 7 * 16384, l2_rev_bl,   u2b, 0);

    // ---- link readout (bf16 gathers, fp32 accum) ----
    dot_kernel<<<(N_LABELS * 32 + 255) / 256, 256, 0, stream>>>(
        u2b, j2b, label_src, label_dst, (float*)d_out, N_LABELS);
}